// Round 3
// baseline (1786.808 us; speedup 1.0000x reference)
//
#include <hip/hip_runtime.h>
#include <math.h>

#define N_NODES 100000
#define N_EDGES 1200000
#define GC 64
#define RBF 32
#define NLAYERS 4
#define NF 92
#define NATOM 100
#define BN_EPS 1e-5f
#define NGROUPS (N_EDGES / 16)   // 75000
#define EDGE_GRID 768            // 768 blocks * 4 waves = 3072 waves (3/SIMD co-resident)

typedef _Float16 half8 __attribute__((ext_vector_type(8)));
typedef _Float16 half4 __attribute__((ext_vector_type(4)));
typedef float f32x4 __attribute__((ext_vector_type(4)));

// ---------- K1: degree histogram ----------
__global__ __launch_bounds__(256) void deg_kernel(
    const int* __restrict__ ei, int* __restrict__ deg)
{
    int e = blockIdx.x * 256 + threadIdx.x;
    if (e >= N_EDGES) return;
    atomicAdd(&deg[ei[N_EDGES + e]], 1);
}

// ---------- scan: block sums ----------
__global__ __launch_bounds__(256) void scan_a_kernel(const int* __restrict__ deg, int* __restrict__ bsums)
{
    __shared__ int sm[256];
    int tid = threadIdx.x;
    int i = blockIdx.x * 256 + tid;
    int v = (i < N_NODES) ? deg[i] : 0;
    sm[tid] = v;
    __syncthreads();
    for (int s = 128; s > 0; s >>= 1) {
        if (tid < s) sm[tid] += sm[tid + s];
        __syncthreads();
    }
    if (tid == 0) bsums[blockIdx.x] = sm[0];
}

__global__ __launch_bounds__(512) void scan_b_kernel(const int* __restrict__ bsums, int* __restrict__ boffs)
{
    __shared__ int sm[512];
    int tid = threadIdx.x;
    int v = (tid < 391) ? bsums[tid] : 0;
    sm[tid] = v;
    __syncthreads();
    for (int off = 1; off < 512; off <<= 1) {
        int t = (tid >= off) ? sm[tid - off] : 0;
        __syncthreads();
        sm[tid] += t;
        __syncthreads();
    }
    boffs[tid] = (tid == 0) ? 0 : sm[tid - 1];
}

__global__ __launch_bounds__(256) void scan_c_kernel(
    const int* __restrict__ deg, const int* __restrict__ boffs,
    int* __restrict__ row_st, float* __restrict__ inv_deg)
{
    __shared__ int sm[256];
    int tid = threadIdx.x;
    int i = blockIdx.x * 256 + tid;
    int v = (i < N_NODES) ? deg[i] : 0;
    sm[tid] = v;
    __syncthreads();
    for (int off = 1; off < 256; off <<= 1) {
        int t = (tid >= off) ? sm[tid - off] : 0;
        __syncthreads();
        sm[tid] += t;
        __syncthreads();
    }
    if (i <= N_NODES) row_st[i] = boffs[blockIdx.x] + sm[tid] - v;  // exclusive
    if (i < N_NODES) inv_deg[i] = (v > 0) ? (1.0f / (float)v) : 0.0f;
}

// ---------- K2: scatter edges into CSR order + fused RBF (fp16) + csr_dst ----------
__global__ __launch_bounds__(256) void scatter_rbf_kernel(
    const int* __restrict__ ei, const float* __restrict__ pos,
    const int* __restrict__ row_st, int* __restrict__ cursor,
    const float* __restrict__ means, const float* __restrict__ betas,
    int* __restrict__ csr_src, int* __restrict__ csr_dst, unsigned int* __restrict__ ea)
{
    int e = blockIdx.x * 256 + threadIdx.x;
    if (e >= N_EDGES) return;
    int s = ei[e];
    int d = ei[N_EDGES + e];
    float dx = pos[s * 3 + 0] - pos[d * 3 + 0];
    float dy = pos[s * 3 + 1] - pos[d * 3 + 1];
    float dz = pos[s * 3 + 2] - pos[d * 3 + 2];
    float dist = sqrtf(dx * dx + dy * dy + dz * dz + 1e-12f);

    int p = atomicAdd(&cursor[d], 1);
    int idx = row_st[d] + p;
    csr_src[idx] = s;
    csr_dst[idx] = d;

    float cut = 0.0f;
    if (dist < 5.0f) cut = 0.5f * (__cosf(dist * 0.6283185307179586f) + 1.0f);
    float ex = __expf(-dist);
    union { _Float16 h[32]; uint4 u[4]; } pk;
#pragma unroll
    for (int k = 0; k < 32; k++) {
        float v = ex - means[k];
        pk.h[k] = (_Float16)(cut * __expf(-betas[k] * v * v));
    }
    uint4* op = (uint4*)(ea + (size_t)idx * 16);
    op[0] = pk.u[0];
    op[1] = pk.u[1];
    op[2] = pk.u[2];
    op[3] = pk.u[3];
}

// ---------- K4a: per-atom-type pre-layer table ----------
__global__ __launch_bounds__(64) void atom_table_kernel(
    const float* __restrict__ emb, const float* __restrict__ pre_W,
    const float* __restrict__ pre_b, float* __restrict__ T)
{
    int a = blockIdx.x;
    int c = threadIdx.x;
    float acc = pre_b[c];
    for (int k = 0; k < NF; k++) acc = fmaf(emb[a * NF + k], pre_W[k * GC + c], acc);
    T[a * GC + c] = fmaxf(acc, 0.0f);
}

// ---------- K4b: broadcast table to nodes (fp32 x and fp16 x16) ----------
__global__ __launch_bounds__(256) void xinit_kernel(
    const int* __restrict__ atom_types, const float* __restrict__ T,
    float* __restrict__ x, _Float16* __restrict__ x16)
{
    int i = blockIdx.x * 256 + threadIdx.x;  // i < N*16 (float4 granules)
    int n = i >> 4;
    int a = atom_types[n];
    float4 v = ((const float4*)T)[a * 16 + (i & 15)];
    ((float4*)x)[i] = v;
    half4 h = { (_Float16)v.x, (_Float16)v.y, (_Float16)v.z, (_Float16)v.w };
    ((half4*)x16)[i] = h;
}

// ---------- K5: edge MFMA + activation + segmented scatter-add ----------
// wave covers 16 CSR-consecutive edges x 32 channels (cthalf selects chan half).
// z = [x16[dst](64) | x16[src](64) | ea(32)], K=160 = 5 ktiles of 32.
__global__ __launch_bounds__(256) void edge_mfma_kernel(
    const _Float16* __restrict__ x16, const _Float16* __restrict__ ea,
    const int* __restrict__ csr_src, const int* __restrict__ csr_dst,
    const float* __restrict__ inv_deg,
    const float* __restrict__ Wf, const float* __restrict__ Ws,   // [160][64]
    const float* __restrict__ bfv, const float* __restrict__ bsv, // [64]
    float* __restrict__ x)
{
    __shared__ float bounce[4][16 * 34];
    const int lane = threadIdx.x & 63;
    const int wid = threadIdx.x >> 6;
    const int quad = lane >> 4;
    const int r16 = lane & 15;

    const int wgid = blockIdx.x * 4 + wid;
    const int cthalf = wgid & 1;
    const int seq = wgid >> 1;
    const int NSEQ = EDGE_GRID * 2;
    const int per = (NGROUPS + NSEQ - 1) / NSEQ;
    const int g0 = seq * per;
    const int g1 = (g0 + per < NGROUPS) ? (g0 + per) : NGROUPS;

    // loop-invariant B fragments: B[n=lane&15][k=quad*8+j]
    half8 Bf[5][2], Bs[5][2];
#pragma unroll
    for (int kt = 0; kt < 5; kt++) {
#pragma unroll
        for (int ctl = 0; ctl < 2; ctl++) {
            int col = cthalf * 32 + ctl * 16 + r16;
            half8 bh, sh;
#pragma unroll
            for (int j = 0; j < 8; j++) {
                int k = kt * 32 + quad * 8 + j;
                bh[j] = (_Float16)Wf[k * GC + col];
                sh[j] = (_Float16)Ws[k * GC + col];
            }
            Bf[kt][ctl] = bh;
            Bs[kt][ctl] = sh;
        }
    }
    float biasf[2], biass[2];
#pragma unroll
    for (int ctl = 0; ctl < 2; ctl++) {
        int col = cthalf * 32 + ctl * 16 + r16;
        biasf[ctl] = bfv[col];
        biass[ctl] = bsv[col];
    }
    const int cb = cthalf * 32;
    float* bb = bounce[wid];

    for (int g = g0; g < g1; g++) {
        const int base = g * 16;
        const int dst = csr_dst[base + r16];
        const int src = csr_src[base + r16];
        half8 A[5];
        A[0] = *(const half8*)(x16 + (size_t)dst * GC + quad * 8);
        A[1] = *(const half8*)(x16 + (size_t)dst * GC + 32 + quad * 8);
        A[2] = *(const half8*)(x16 + (size_t)src * GC + quad * 8);
        A[3] = *(const half8*)(x16 + (size_t)src * GC + 32 + quad * 8);
        A[4] = *(const half8*)(ea + (size_t)(base + r16) * RBF + quad * 8);

        f32x4 cf[2], cs2[2];
#pragma unroll
        for (int ctl = 0; ctl < 2; ctl++) { cf[ctl] = (f32x4){0.f, 0.f, 0.f, 0.f}; cs2[ctl] = (f32x4){0.f, 0.f, 0.f, 0.f}; }
#pragma unroll
        for (int kt = 0; kt < 5; kt++) {
#pragma unroll
            for (int ctl = 0; ctl < 2; ctl++) {
                cf[ctl] = __builtin_amdgcn_mfma_f32_16x16x32_f16(A[kt], Bf[kt][ctl], cf[ctl], 0, 0, 0);
                cs2[ctl] = __builtin_amdgcn_mfma_f32_16x16x32_f16(A[kt], Bs[kt][ctl], cs2[ctl], 0, 0, 0);
            }
        }
        // activation; C layout: col=lane&15 (chan), row=quad*4+reg (edge)
#pragma unroll
        for (int ctl = 0; ctl < 2; ctl++) {
#pragma unroll
            for (int rr = 0; rr < 4; rr++) {
                float af = cf[ctl][rr] + biasf[ctl];
                float as = cs2[ctl][rr] + biass[ctl];
                float sg = 1.0f / (1.0f + __expf(-af));
                float sp = fmaxf(as, 0.0f) + __logf(1.0f + __expf(-fabsf(as)));
                int e = quad * 4 + rr;
                bb[e * 34 + ctl * 16 + r16] = sg * sp;
            }
        }
        // segmented scan over the 16 edges (dst non-decreasing in CSR order)
        if (lane < 32) {
            int prev = __shfl(dst, 0);
            float run = 0.0f;
#pragma unroll
            for (int e = 0; e < 16; e++) {
                int de = __shfl(dst, e);
                float v = bb[e * 34 + lane];
                if (de != prev) {
                    atomicAdd(&x[(size_t)prev * GC + cb + lane], run * inv_deg[prev]);
                    run = 0.0f;
                    prev = de;
                }
                run += v;
            }
            atomicAdd(&x[(size_t)prev * GC + cb + lane], run * inv_deg[prev]);
        }
    }
}

// ---------- K6: BN stats ----------
__global__ __launch_bounds__(256) void stats_kernel(const float* __restrict__ x, float* __restrict__ stats)
{
    const int lane = threadIdx.x & 63;
    const int wid = threadIdx.x >> 6;
    int w = blockIdx.x * 4 + wid;  // 0..1023
    float s1 = 0.0f, s2 = 0.0f;
    for (int n = w; n < N_NODES; n += 1024) {
        float v = x[(size_t)n * GC + lane];
        s1 += v;
        s2 = fmaf(v, v, s2);
    }
    __shared__ float rs1[4][64];
    __shared__ float rs2[4][64];
    rs1[wid][lane] = s1;
    rs2[wid][lane] = s2;
    __syncthreads();
    if (threadIdx.x < 64) {
        atomicAdd(&stats[lane], rs1[0][lane] + rs1[1][lane] + rs1[2][lane] + rs1[3][lane]);
    } else if (threadIdx.x < 128) {
        int c = threadIdx.x & 63;
        atomicAdd(&stats[64 + c], rs2[0][c] + rs2[1][c] + rs2[2][c] + rs2[3][c]);
    }
}

// ---------- K7: batchnorm apply (writes fp32 out and fp16 x16) ----------
__global__ __launch_bounds__(256) void bn_kernel(
    const float* __restrict__ xn, const float* __restrict__ stats,
    const float* __restrict__ gamma, const float* __restrict__ beta,
    float* __restrict__ out, _Float16* __restrict__ out16)
{
    int i = blockIdx.x * 256 + threadIdx.x;  // i < N*16
    int c4 = (i & 15) * 4;
    float4 v = ((const float4*)xn)[i];
    float vv[4] = {v.x, v.y, v.z, v.w};
    float o[4];
    const float invN = 1.0f / (float)N_NODES;
#pragma unroll
    for (int t = 0; t < 4; t++) {
        int c = c4 + t;
        float mu = stats[c] * invN;
        float var = stats[64 + c] * invN - mu * mu;
        float sc = gamma[c] * rsqrtf(var + BN_EPS);
        o[t] = (vv[t] - mu) * sc + beta[c];
    }
    ((float4*)out)[i] = make_float4(o[0], o[1], o[2], o[3]);
    half4 h = { (_Float16)o[0], (_Float16)o[1], (_Float16)o[2], (_Float16)o[3] };
    ((half4*)out16)[i] = h;
}

extern "C" void kernel_launch(void* const* d_in, const int* in_sizes, int n_in,
                              void* d_out, int out_size, void* d_ws, size_t ws_size,
                              hipStream_t stream)
{
    const int* atom_types = (const int*)d_in[0];
    const float* pos = (const float*)d_in[1];
    const int* edge_index = (const int*)d_in[2];
    const float* emb = (const float*)d_in[3];
    const float* pre_W = (const float*)d_in[4];
    const float* pre_b = (const float*)d_in[5];
    const float* Wf = (const float*)d_in[6];
    const float* bf = (const float*)d_in[7];
    const float* Ws = (const float*)d_in[8];
    const float* bs = (const float*)d_in[9];
    const float* gamma = (const float*)d_in[10];
    const float* beta = (const float*)d_in[11];
    const float* means = (const float*)d_in[12];
    const float* betas = (const float*)d_in[13];

    char* base = (char*)d_ws;
    char* p = base;
    auto alloc = [&](size_t bytes) -> char* {
        char* r = p;
        p += (bytes + 255) & ~(size_t)255;
        return r;
    };
    unsigned int* ea = (unsigned int*)alloc((size_t)N_EDGES * RBF * 2);   // 76.8 MB fp16
    float* x = (float*)alloc((size_t)N_NODES * GC * 4);                   // 25.6 MB
    _Float16* x16 = (_Float16*)alloc((size_t)N_NODES * GC * 2);           // 12.8 MB
    int* csr_src = (int*)alloc((size_t)N_EDGES * 4);                      // 4.8 MB
    int* csr_dst = (int*)alloc((size_t)N_EDGES * 4);                      // 4.8 MB
    int* row_st = (int*)alloc((size_t)(N_NODES + 1) * 4);
    float* inv_deg = (float*)alloc((size_t)N_NODES * 4);
    float* T = (float*)alloc((size_t)NATOM * GC * 4);
    int* bsums = (int*)alloc(512 * 4);
    int* boffs = (int*)alloc(512 * 4);
    char* zr = alloc((size_t)(2 * N_NODES + 128 * NLAYERS) * 4);
    int* deg = (int*)zr;
    int* cursor = deg + N_NODES;
    float* stats = (float*)(cursor + N_NODES);

    if ((size_t)(p - base) > ws_size) return;  // diagnostic bail: leaves poison in d_out

    hipMemsetAsync(zr, 0, (size_t)(2 * N_NODES + 128 * NLAYERS) * 4, stream);

    const int EG = (N_EDGES + 255) / 256;
    deg_kernel<<<EG, 256, 0, stream>>>(edge_index, deg);
    scan_a_kernel<<<391, 256, 0, stream>>>(deg, bsums);
    scan_b_kernel<<<1, 512, 0, stream>>>(bsums, boffs);
    scan_c_kernel<<<391, 256, 0, stream>>>(deg, boffs, row_st, inv_deg);
    scatter_rbf_kernel<<<EG, 256, 0, stream>>>(edge_index, pos, row_st, cursor,
                                               means, betas, csr_src, csr_dst, ea);
    atom_table_kernel<<<NATOM, 64, 0, stream>>>(emb, pre_W, pre_b, T);
    xinit_kernel<<<N_NODES * 16 / 256, 256, 0, stream>>>(atom_types, T, x, x16);

    for (int l = 0; l < NLAYERS; l++) {
        const float* Wfl = Wf + (size_t)l * 160 * GC;
        const float* Wsl = Ws + (size_t)l * 160 * GC;
        edge_mfma_kernel<<<EDGE_GRID, 256, 0, stream>>>(
            x16, (const _Float16*)ea, csr_src, csr_dst, inv_deg,
            Wfl, Wsl, bf + l * GC, bs + l * GC, x);
        stats_kernel<<<256, 256, 0, stream>>>(x, stats + l * 128);
        bn_kernel<<<N_NODES * 16 / 256, 256, 0, stream>>>(
            x, stats + l * 128, gamma + l * GC, beta + l * GC,
            (l == NLAYERS - 1) ? (float*)d_out : x, x16);
    }
}

// Round 4
// 1309.224 us; speedup vs baseline: 1.3648x; 1.3648x over previous
//
#include <hip/hip_runtime.h>
#include <math.h>

#define N_NODES 100000
#define N_EDGES 1200000
#define GC 64
#define RBF 32
#define NLAYERS 4
#define NF 92
#define NATOM 100
#define BN_EPS 1e-5f
#define NODE_GRID 2048
#define NPAIRS (NODE_GRID * 2)   // wave-pairs striding nodes

typedef _Float16 half8 __attribute__((ext_vector_type(8)));
typedef _Float16 half4 __attribute__((ext_vector_type(4)));
typedef float f32x4 __attribute__((ext_vector_type(4)));

// ---------- K1: degree histogram ----------
__global__ __launch_bounds__(256) void deg_kernel(
    const int* __restrict__ ei, int* __restrict__ deg)
{
    int e = blockIdx.x * 256 + threadIdx.x;
    if (e >= N_EDGES) return;
    atomicAdd(&deg[ei[N_EDGES + e]], 1);
}

// ---------- scan: block sums ----------
__global__ __launch_bounds__(256) void scan_a_kernel(const int* __restrict__ deg, int* __restrict__ bsums)
{
    __shared__ int sm[256];
    int tid = threadIdx.x;
    int i = blockIdx.x * 256 + tid;
    int v = (i < N_NODES) ? deg[i] : 0;
    sm[tid] = v;
    __syncthreads();
    for (int s = 128; s > 0; s >>= 1) {
        if (tid < s) sm[tid] += sm[tid + s];
        __syncthreads();
    }
    if (tid == 0) bsums[blockIdx.x] = sm[0];
}

__global__ __launch_bounds__(512) void scan_b_kernel(const int* __restrict__ bsums, int* __restrict__ boffs)
{
    __shared__ int sm[512];
    int tid = threadIdx.x;
    int v = (tid < 391) ? bsums[tid] : 0;
    sm[tid] = v;
    __syncthreads();
    for (int off = 1; off < 512; off <<= 1) {
        int t = (tid >= off) ? sm[tid - off] : 0;
        __syncthreads();
        sm[tid] += t;
        __syncthreads();
    }
    boffs[tid] = (tid == 0) ? 0 : sm[tid - 1];
}

__global__ __launch_bounds__(256) void scan_c_kernel(
    const int* __restrict__ deg, const int* __restrict__ boffs,
    int* __restrict__ row_st)
{
    __shared__ int sm[256];
    int tid = threadIdx.x;
    int i = blockIdx.x * 256 + tid;
    int v = (i < N_NODES) ? deg[i] : 0;
    sm[tid] = v;
    __syncthreads();
    for (int off = 1; off < 256; off <<= 1) {
        int t = (tid >= off) ? sm[tid - off] : 0;
        __syncthreads();
        sm[tid] += t;
        __syncthreads();
    }
    if (i <= N_NODES) row_st[i] = boffs[blockIdx.x] + sm[tid] - v;  // exclusive
}

// ---------- K2: scatter edges into CSR order + fused RBF (fp16) ----------
__global__ __launch_bounds__(256) void scatter_rbf_kernel(
    const int* __restrict__ ei, const float* __restrict__ pos,
    const int* __restrict__ row_st, int* __restrict__ cursor,
    const float* __restrict__ means, const float* __restrict__ betas,
    int* __restrict__ csr_src, unsigned int* __restrict__ ea)
{
    int e = blockIdx.x * 256 + threadIdx.x;
    if (e >= N_EDGES) return;
    int s = ei[e];
    int d = ei[N_EDGES + e];
    float dx = pos[s * 3 + 0] - pos[d * 3 + 0];
    float dy = pos[s * 3 + 1] - pos[d * 3 + 1];
    float dz = pos[s * 3 + 2] - pos[d * 3 + 2];
    float dist = sqrtf(dx * dx + dy * dy + dz * dz + 1e-12f);

    int p = atomicAdd(&cursor[d], 1);
    int idx = row_st[d] + p;
    csr_src[idx] = s;

    float cut = 0.0f;
    if (dist < 5.0f) cut = 0.5f * (__cosf(dist * 0.6283185307179586f) + 1.0f);
    float ex = __expf(-dist);
    union { _Float16 h[32]; uint4 u[4]; } pk;
#pragma unroll
    for (int k = 0; k < 32; k++) {
        float v = ex - means[k];
        pk.h[k] = (_Float16)(cut * __expf(-betas[k] * v * v));
    }
    uint4* op = (uint4*)(ea + (size_t)idx * 16);
    op[0] = pk.u[0];
    op[1] = pk.u[1];
    op[2] = pk.u[2];
    op[3] = pk.u[3];
}

// ---------- K4a: per-atom-type pre-layer table ----------
__global__ __launch_bounds__(64) void atom_table_kernel(
    const float* __restrict__ emb, const float* __restrict__ pre_W,
    const float* __restrict__ pre_b, float* __restrict__ T)
{
    int a = blockIdx.x;
    int c = threadIdx.x;
    float acc = pre_b[c];
    for (int k = 0; k < NF; k++) acc = fmaf(emb[a * NF + k], pre_W[k * GC + c], acc);
    T[a * GC + c] = fmaxf(acc, 0.0f);
}

// ---------- K4b: broadcast table to nodes (fp32 x and fp16 x16) ----------
__global__ __launch_bounds__(256) void xinit_kernel(
    const int* __restrict__ atom_types, const float* __restrict__ T,
    float* __restrict__ x, _Float16* __restrict__ x16)
{
    int i = blockIdx.x * 256 + threadIdx.x;  // i < N*16 (float4 granules)
    int n = i >> 4;
    int a = atom_types[n];
    float4 v = ((const float4*)T)[a * 16 + (i & 15)];
    ((float4*)x)[i] = v;
    half4 h = { (_Float16)v.x, (_Float16)v.y, (_Float16)v.z, (_Float16)v.w };
    ((half4*)x16)[i] = h;
}

// ---------- K5: node-centric MFMA CGConv layer ----------
// Wave-pair per node (cthalf = channel half). Tiles of 16 edges of one node.
// z = [x16[n](64) | x16[src](64) | ea(32)], K=160 = 5 ktiles of 32.
// No atomics / LDS / scan in hot loop; reduction via shfl_xor; wave owns node.
__global__ __launch_bounds__(256) void node_mfma_kernel(
    const _Float16* __restrict__ x16, const _Float16* __restrict__ ea,
    const int* __restrict__ csr_src, const int* __restrict__ row_st,
    const float* __restrict__ Wf, const float* __restrict__ Ws,   // [160][64]
    const float* __restrict__ bfv, const float* __restrict__ bsv, // [64]
    float* __restrict__ x, float* __restrict__ stats)
{
    const int lane = threadIdx.x & 63;
    const int wid = threadIdx.x >> 6;
    const int quad = lane >> 4;
    const int r16 = lane & 15;

    const int wgid = blockIdx.x * 4 + wid;
    const int cthalf = wgid & 1;
    const int pair = wgid >> 1;

    // loop-invariant B fragments: B[n=lane&15 -> chan][k=quad*8+j]
    half8 Bf[5][2], Bs[5][2];
#pragma unroll
    for (int kt = 0; kt < 5; kt++) {
#pragma unroll
        for (int ctl = 0; ctl < 2; ctl++) {
            int col = cthalf * 32 + ctl * 16 + r16;
            half8 bh, sh;
#pragma unroll
            for (int j = 0; j < 8; j++) {
                int k = kt * 32 + quad * 8 + j;
                bh[j] = (_Float16)Wf[k * GC + col];
                sh[j] = (_Float16)Ws[k * GC + col];
            }
            Bf[kt][ctl] = bh;
            Bs[kt][ctl] = sh;
        }
    }
    float biasf[2], biass[2];
#pragma unroll
    for (int ctl = 0; ctl < 2; ctl++) {
        int col = cthalf * 32 + ctl * 16 + r16;
        biasf[ctl] = bfv[col];
        biass[ctl] = bsv[col];
    }

    float s1 = 0.0f, s2 = 0.0f;  // BN stats (lanes<32 meaningful)

    for (int n = pair; n < N_NODES; n += NPAIRS) {
        const int row = row_st[n];          // wave-uniform scalar loads
        const int deg = row_st[n + 1] - row;
        const int tiles = (deg + 15) >> 4;

        // dst fragments: wave-uniform, hoisted out of tile loop
        half8 A0 = *(const half8*)(x16 + (size_t)n * GC + quad * 8);
        half8 A1 = *(const half8*)(x16 + (size_t)n * GC + 32 + quad * 8);

        float acc0 = 0.0f, acc1 = 0.0f;

        half8 P2, P3, P4;  // prefetched src/ea fragments
        if (tiles > 0) {
            int e = r16;  // t=0
            int j = row + (e < deg ? e : deg - 1);
            int src = csr_src[j];
            P2 = *(const half8*)(x16 + (size_t)src * GC + quad * 8);
            P3 = *(const half8*)(x16 + (size_t)src * GC + 32 + quad * 8);
            P4 = *(const half8*)(ea + (size_t)j * RBF + quad * 8);
        }
        for (int t = 0; t < tiles; t++) {
            half8 C2 = P2, C3 = P3, C4 = P4;
            if (t + 1 < tiles) {
                int e = (t + 1) * 16 + r16;
                int j = row + (e < deg ? e : deg - 1);
                int src = csr_src[j];
                P2 = *(const half8*)(x16 + (size_t)src * GC + quad * 8);
                P3 = *(const half8*)(x16 + (size_t)src * GC + 32 + quad * 8);
                P4 = *(const half8*)(ea + (size_t)j * RBF + quad * 8);
            }
            f32x4 cf[2], cs[2];
#pragma unroll
            for (int ctl = 0; ctl < 2; ctl++) {
                cf[ctl] = (f32x4){0.f, 0.f, 0.f, 0.f};
                cs[ctl] = (f32x4){0.f, 0.f, 0.f, 0.f};
            }
#pragma unroll
            for (int ctl = 0; ctl < 2; ctl++) {
                cf[ctl] = __builtin_amdgcn_mfma_f32_16x16x32_f16(A0, Bf[0][ctl], cf[ctl], 0, 0, 0);
                cs[ctl] = __builtin_amdgcn_mfma_f32_16x16x32_f16(A0, Bs[0][ctl], cs[ctl], 0, 0, 0);
                cf[ctl] = __builtin_amdgcn_mfma_f32_16x16x32_f16(A1, Bf[1][ctl], cf[ctl], 0, 0, 0);
                cs[ctl] = __builtin_amdgcn_mfma_f32_16x16x32_f16(A1, Bs[1][ctl], cs[ctl], 0, 0, 0);
                cf[ctl] = __builtin_amdgcn_mfma_f32_16x16x32_f16(C2, Bf[2][ctl], cf[ctl], 0, 0, 0);
                cs[ctl] = __builtin_amdgcn_mfma_f32_16x16x32_f16(C2, Bs[2][ctl], cs[ctl], 0, 0, 0);
                cf[ctl] = __builtin_amdgcn_mfma_f32_16x16x32_f16(C3, Bf[3][ctl], cf[ctl], 0, 0, 0);
                cs[ctl] = __builtin_amdgcn_mfma_f32_16x16x32_f16(C3, Bs[3][ctl], cs[ctl], 0, 0, 0);
                cf[ctl] = __builtin_amdgcn_mfma_f32_16x16x32_f16(C4, Bf[4][ctl], cf[ctl], 0, 0, 0);
                cs[ctl] = __builtin_amdgcn_mfma_f32_16x16x32_f16(C4, Bs[4][ctl], cs[ctl], 0, 0, 0);
            }
            // C layout: col(lane&15)=chan, row(quad*4+rr)=edge within tile
#pragma unroll
            for (int ctl = 0; ctl < 2; ctl++) {
#pragma unroll
                for (int rr = 0; rr < 4; rr++) {
                    float af = cf[ctl][rr] + biasf[ctl];
                    float as = cs[ctl][rr] + biass[ctl];
                    float sg = 1.0f / (1.0f + __expf(-af));
                    float sp = fmaxf(as, 0.0f) + __logf(1.0f + __expf(-fabsf(as)));
                    int ee = t * 16 + quad * 4 + rr;
                    float msg = (ee < deg) ? sg * sp : 0.0f;
                    if (ctl == 0) acc0 += msg; else acc1 += msg;
                }
            }
        }
        // fold the 4 quad partials (each quad held 4 of the 16 edge rows)
        acc0 += __shfl_xor(acc0, 16);
        acc0 += __shfl_xor(acc0, 32);
        acc1 += __shfl_xor(acc1, 16);
        acc1 += __shfl_xor(acc1, 32);

        if (lane < 32) {
            float inv = (deg > 0) ? (1.0f / (float)deg) : 0.0f;
            float accs = (lane < 16) ? acc0 : acc1;
            size_t ix = (size_t)n * GC + cthalf * 32 + lane;
            float xn = fmaf(accs, inv, x[ix]);
            x[ix] = xn;
            s1 += xn;
            s2 = fmaf(xn, xn, s2);
        }
    }

    // block-level BN-stats reduction (chan c: wid0/2 -> cthalf0 (c<32), wid1/3 -> cthalf1)
    __shared__ float rs1[4][32];
    __shared__ float rs2[4][32];
    if (lane < 32) {
        rs1[wid][lane] = s1;
        rs2[wid][lane] = s2;
    }
    __syncthreads();
    int t = threadIdx.x;
    if (t < 64) {
        float v = (t < 32) ? (rs1[0][t] + rs1[2][t]) : (rs1[1][t & 31] + rs1[3][t & 31]);
        atomicAdd(&stats[t], v);
    } else if (t < 128) {
        int c = t - 64;
        float v = (c < 32) ? (rs2[0][c] + rs2[2][c]) : (rs2[1][c & 31] + rs2[3][c & 31]);
        atomicAdd(&stats[64 + c], v);
    }
}

// ---------- K7: batchnorm apply (writes fp32 out and fp16 x16) ----------
__global__ __launch_bounds__(256) void bn_kernel(
    const float* __restrict__ xn, const float* __restrict__ stats,
    const float* __restrict__ gamma, const float* __restrict__ beta,
    float* __restrict__ out, _Float16* __restrict__ out16)
{
    int i = blockIdx.x * 256 + threadIdx.x;  // i < N*16
    int c4 = (i & 15) * 4;
    float4 v = ((const float4*)xn)[i];
    float vv[4] = {v.x, v.y, v.z, v.w};
    float o[4];
    const float invN = 1.0f / (float)N_NODES;
#pragma unroll
    for (int t = 0; t < 4; t++) {
        int c = c4 + t;
        float mu = stats[c] * invN;
        float var = stats[64 + c] * invN - mu * mu;
        float sc = gamma[c] * rsqrtf(var + BN_EPS);
        o[t] = (vv[t] - mu) * sc + beta[c];
    }
    ((float4*)out)[i] = make_float4(o[0], o[1], o[2], o[3]);
    half4 h = { (_Float16)o[0], (_Float16)o[1], (_Float16)o[2], (_Float16)o[3] };
    ((half4*)out16)[i] = h;
}

extern "C" void kernel_launch(void* const* d_in, const int* in_sizes, int n_in,
                              void* d_out, int out_size, void* d_ws, size_t ws_size,
                              hipStream_t stream)
{
    const int* atom_types = (const int*)d_in[0];
    const float* pos = (const float*)d_in[1];
    const int* edge_index = (const int*)d_in[2];
    const float* emb = (const float*)d_in[3];
    const float* pre_W = (const float*)d_in[4];
    const float* pre_b = (const float*)d_in[5];
    const float* Wf = (const float*)d_in[6];
    const float* bf = (const float*)d_in[7];
    const float* Ws = (const float*)d_in[8];
    const float* bs = (const float*)d_in[9];
    const float* gamma = (const float*)d_in[10];
    const float* beta = (const float*)d_in[11];
    const float* means = (const float*)d_in[12];
    const float* betas = (const float*)d_in[13];

    char* base = (char*)d_ws;
    char* p = base;
    auto alloc = [&](size_t bytes) -> char* {
        char* r = p;
        p += (bytes + 255) & ~(size_t)255;
        return r;
    };
    unsigned int* ea = (unsigned int*)alloc((size_t)N_EDGES * RBF * 2);   // 76.8 MB fp16
    float* x = (float*)alloc((size_t)N_NODES * GC * 4);                   // 25.6 MB
    _Float16* x16 = (_Float16*)alloc((size_t)N_NODES * GC * 2);           // 12.8 MB
    int* csr_src = (int*)alloc((size_t)N_EDGES * 4);                      // 4.8 MB
    int* row_st = (int*)alloc((size_t)(N_NODES + 1) * 4);
    float* T = (float*)alloc((size_t)NATOM * GC * 4);
    int* bsums = (int*)alloc(512 * 4);
    int* boffs = (int*)alloc(512 * 4);
    char* zr = alloc((size_t)(2 * N_NODES + 128 * NLAYERS) * 4);
    int* deg = (int*)zr;
    int* cursor = deg + N_NODES;
    float* stats = (float*)(cursor + N_NODES);

    if ((size_t)(p - base) > ws_size) return;  // diagnostic bail: leaves poison in d_out

    hipMemsetAsync(zr, 0, (size_t)(2 * N_NODES + 128 * NLAYERS) * 4, stream);

    const int EG = (N_EDGES + 255) / 256;
    deg_kernel<<<EG, 256, 0, stream>>>(edge_index, deg);
    scan_a_kernel<<<391, 256, 0, stream>>>(deg, bsums);
    scan_b_kernel<<<1, 512, 0, stream>>>(bsums, boffs);
    scan_c_kernel<<<391, 256, 0, stream>>>(deg, boffs, row_st);
    scatter_rbf_kernel<<<EG, 256, 0, stream>>>(edge_index, pos, row_st, cursor,
                                               means, betas, csr_src, ea);
    atom_table_kernel<<<NATOM, 64, 0, stream>>>(emb, pre_W, pre_b, T);
    xinit_kernel<<<N_NODES * 16 / 256, 256, 0, stream>>>(atom_types, T, x, x16);

    for (int l = 0; l < NLAYERS; l++) {
        const float* Wfl = Wf + (size_t)l * 160 * GC;
        const float* Wsl = Ws + (size_t)l * 160 * GC;
        node_mfma_kernel<<<NODE_GRID, 256, 0, stream>>>(
            x16, (const _Float16*)ea, csr_src, row_st,
            Wfl, Wsl, bf + l * GC, bs + l * GC, x, stats + l * 128);
        bn_kernel<<<N_NODES * 16 / 256, 256, 0, stream>>>(
            x, stats + l * 128, gamma + l * GC, beta + l * GC,
            (l == NLAYERS - 1) ? (float*)d_out : x, x16);
    }
}

// Round 5
// 1123.912 us; speedup vs baseline: 1.5898x; 1.1649x over previous
//
#include <hip/hip_runtime.h>
#include <math.h>

#define N_NODES 100000
#define N_EDGES 1200000
#define GC 64
#define RBF 32
#define NLAYERS 4
#define NF 92
#define NATOM 100
#define BN_EPS 1e-5f
#define TILE_GRID 2048
#define NTILE_MAX 220000   // >= N_NODES + E/16 upper bound with margin

typedef _Float16 half8 __attribute__((ext_vector_type(8)));
typedef _Float16 half4 __attribute__((ext_vector_type(4)));
typedef float f32x4 __attribute__((ext_vector_type(4)));

// ---------- K1: degree histogram ----------
__global__ __launch_bounds__(256) void deg_kernel(
    const int* __restrict__ ei, int* __restrict__ deg)
{
    int e = blockIdx.x * 256 + threadIdx.x;
    if (e >= N_EDGES) return;
    atomicAdd(&deg[ei[N_EDGES + e]], 1);
}

// ---------- scan: block sums ----------
__global__ __launch_bounds__(256) void scan_a_kernel(const int* __restrict__ deg, int* __restrict__ bsums)
{
    __shared__ int sm[256];
    int tid = threadIdx.x;
    int i = blockIdx.x * 256 + tid;
    int v = (i < N_NODES) ? deg[i] : 0;
    sm[tid] = v;
    __syncthreads();
    for (int s = 128; s > 0; s >>= 1) {
        if (tid < s) sm[tid] += sm[tid + s];
        __syncthreads();
    }
    if (tid == 0) bsums[blockIdx.x] = sm[0];
}

__global__ __launch_bounds__(512) void scan_b_kernel(const int* __restrict__ bsums, int* __restrict__ boffs)
{
    __shared__ int sm[512];
    int tid = threadIdx.x;
    int v = (tid < 391) ? bsums[tid] : 0;
    sm[tid] = v;
    __syncthreads();
    for (int off = 1; off < 512; off <<= 1) {
        int t = (tid >= off) ? sm[tid - off] : 0;
        __syncthreads();
        sm[tid] += t;
        __syncthreads();
    }
    boffs[tid] = (tid == 0) ? 0 : sm[tid - 1];
}

__global__ __launch_bounds__(256) void scan_c_kernel(
    const int* __restrict__ deg, const int* __restrict__ boffs,
    int* __restrict__ row_st, float* __restrict__ inv_deg)
{
    __shared__ int sm[256];
    int tid = threadIdx.x;
    int i = blockIdx.x * 256 + tid;
    int v = (i < N_NODES) ? deg[i] : 0;
    sm[tid] = v;
    __syncthreads();
    for (int off = 1; off < 256; off <<= 1) {
        int t = (tid >= off) ? sm[tid - off] : 0;
        __syncthreads();
        sm[tid] += t;
        __syncthreads();
    }
    if (i <= N_NODES) row_st[i] = boffs[blockIdx.x] + sm[tid] - v;  // exclusive
    if (i < N_NODES) inv_deg[i] = (v > 0) ? (1.0f / (float)v) : 0.0f;
}

// ---------- K2: scatter edges into CSR order + fused RBF (fp16) ----------
__global__ __launch_bounds__(256) void scatter_rbf_kernel(
    const int* __restrict__ ei, const float* __restrict__ pos,
    const int* __restrict__ row_st, int* __restrict__ cursor,
    const float* __restrict__ means, const float* __restrict__ betas,
    int* __restrict__ csr_src, unsigned int* __restrict__ ea)
{
    int e = blockIdx.x * 256 + threadIdx.x;
    if (e >= N_EDGES) return;
    int s = ei[e];
    int d = ei[N_EDGES + e];
    float dx = pos[s * 3 + 0] - pos[d * 3 + 0];
    float dy = pos[s * 3 + 1] - pos[d * 3 + 1];
    float dz = pos[s * 3 + 2] - pos[d * 3 + 2];
    float dist = sqrtf(dx * dx + dy * dy + dz * dz + 1e-12f);

    int p = atomicAdd(&cursor[d], 1);
    int idx = row_st[d] + p;
    csr_src[idx] = s;

    float cut = 0.0f;
    if (dist < 5.0f) cut = 0.5f * (__cosf(dist * 0.6283185307179586f) + 1.0f);
    float ex = __expf(-dist);
    union { _Float16 h[32]; uint4 u[4]; } pk;
#pragma unroll
    for (int k = 0; k < 32; k++) {
        float v = ex - means[k];
        pk.h[k] = (_Float16)(cut * __expf(-betas[k] * v * v));
    }
    uint4* op = (uint4*)(ea + (size_t)idx * 16);
    op[0] = pk.u[0];
    op[1] = pk.u[1];
    op[2] = pk.u[2];
    op[3] = pk.u[3];
}

// ---------- K3: flat tile-descriptor list ----------
__global__ __launch_bounds__(256) void tile_build_kernel(
    const int* __restrict__ row_st, int2* __restrict__ tdesc, int* __restrict__ tcount)
{
    int n = blockIdx.x * 256 + threadIdx.x;
    if (n >= N_NODES) return;
    int row = row_st[n];
    int dg = row_st[n + 1] - row;
    int tiles = (dg + 15) >> 4;
    if (tiles == 0) return;
    int base = atomicAdd(tcount, tiles);
    for (int t = 0; t < tiles; t++) {
        int cnt = dg - 16 * t;
        if (cnt > 16) cnt = 16;
        tdesc[base + t] = make_int2(row + 16 * t, (n << 5) | cnt);
    }
}

// ---------- K4a: per-atom-type pre-layer table ----------
__global__ __launch_bounds__(64) void atom_table_kernel(
    const float* __restrict__ emb, const float* __restrict__ pre_W,
    const float* __restrict__ pre_b, float* __restrict__ T)
{
    int a = blockIdx.x;
    int c = threadIdx.x;
    float acc = pre_b[c];
    for (int k = 0; k < NF; k++) acc = fmaf(emb[a * NF + k], pre_W[k * GC + c], acc);
    T[a * GC + c] = fmaxf(acc, 0.0f);
}

// ---------- K4b: broadcast table to nodes (fp32 x and fp16 x16) ----------
__global__ __launch_bounds__(256) void xinit_kernel(
    const int* __restrict__ atom_types, const float* __restrict__ T,
    float* __restrict__ x, _Float16* __restrict__ x16)
{
    int i = blockIdx.x * 256 + threadIdx.x;  // i < N*16 (float4 granules)
    int n = i >> 4;
    int a = atom_types[n];
    float4 v = ((const float4*)T)[a * 16 + (i & 15)];
    ((float4*)x)[i] = v;
    half4 h = { (_Float16)v.x, (_Float16)v.y, (_Float16)v.z, (_Float16)v.w };
    ((half4*)x16)[i] = h;
}

// ---------- K5: flat-tile MFMA CGConv layer, 3-deep cross-tile pipeline ----------
// Wave-pair per tile (cthalf = channel half). Tile = up to 16 edges of one node.
// z = [x16[n](64) | x16[src](64) | ea(32)], K=160 = 5 ktiles of 32.
// x holds the residual; each tile atomically adds its partial * inv_deg.
__global__ __launch_bounds__(256) void tile_mfma_kernel(
    const _Float16* __restrict__ x16, const _Float16* __restrict__ ea,
    const int* __restrict__ csr_src, const int2* __restrict__ tdesc,
    const int* __restrict__ tcount, const float* __restrict__ inv_deg,
    const float* __restrict__ Wf, const float* __restrict__ Ws,   // [160][64]
    const float* __restrict__ bfv, const float* __restrict__ bsv, // [64]
    float* __restrict__ x)
{
    const int lane = threadIdx.x & 63;
    const int wid = threadIdx.x >> 6;
    const int quad = lane >> 4;
    const int r16 = lane & 15;

    const int wgid = blockIdx.x * 4 + wid;
    const int cthalf = wgid & 1;
    const int seq = wgid >> 1;
    const int NSEQ = TILE_GRID * 2;

    // loop-invariant B fragments: B[n=lane&15 -> chan][k=quad*8+j]
    half8 Bf[5][2], Bs[5][2];
#pragma unroll
    for (int kt = 0; kt < 5; kt++) {
#pragma unroll
        for (int ctl = 0; ctl < 2; ctl++) {
            int col = cthalf * 32 + ctl * 16 + r16;
            half8 bh, sh;
#pragma unroll
            for (int j = 0; j < 8; j++) {
                int k = kt * 32 + quad * 8 + j;
                bh[j] = (_Float16)Wf[k * GC + col];
                sh[j] = (_Float16)Ws[k * GC + col];
            }
            Bf[kt][ctl] = bh;
            Bs[kt][ctl] = sh;
        }
    }
    float biasf[2], biass[2];
#pragma unroll
    for (int ctl = 0; ctl < 2; ctl++) {
        int col = cthalf * 32 + ctl * 16 + r16;
        biasf[ctl] = bfv[col];
        biass[ctl] = bsv[col];
    }

    const int nt = tcount[0];
    if (seq >= nt) return;

    // ---- prologue: tile T fully, T+1 meta+csr, T+2 desc ----
    int idx = seq;
    int2 d0 = tdesc[idx];
    int n0 = d0.y >> 5, c0 = d0.y & 31;
    int j0 = d0.x + (r16 < c0 ? r16 : c0 - 1);
    float inv0 = inv_deg[n0];
    int s0 = csr_src[j0];
    half8 cA0 = *(const half8*)(x16 + (size_t)n0 * GC + quad * 8);
    half8 cA1 = *(const half8*)(x16 + (size_t)n0 * GC + 32 + quad * 8);
    half8 cP2 = *(const half8*)(x16 + (size_t)s0 * GC + quad * 8);
    half8 cP3 = *(const half8*)(x16 + (size_t)s0 * GC + 32 + quad * 8);
    half8 cP4 = *(const half8*)(ea + (size_t)j0 * RBF + quad * 8);

    int idx1 = idx + NSEQ;
    int2 d1 = tdesc[idx1 < nt ? idx1 : nt - 1];
    int n1 = d1.y >> 5, c1 = d1.y & 31;
    int j1 = d1.x + (r16 < c1 ? r16 : c1 - 1);
    int s1 = csr_src[j1];
    float inv1 = inv_deg[n1];

    int idx2 = idx1 + NSEQ;
    int2 d2 = tdesc[idx2 < nt ? idx2 : nt - 1];

    while (true) {
        // issue T+1 fragment loads (addresses ready since last iteration)
        half8 nA0 = *(const half8*)(x16 + (size_t)n1 * GC + quad * 8);
        half8 nA1 = *(const half8*)(x16 + (size_t)n1 * GC + 32 + quad * 8);
        half8 nP2 = *(const half8*)(x16 + (size_t)s1 * GC + quad * 8);
        half8 nP3 = *(const half8*)(x16 + (size_t)s1 * GC + 32 + quad * 8);
        half8 nP4 = *(const half8*)(ea + (size_t)j1 * RBF + quad * 8);

        // T+2 meta: issue csr load (desc was loaded last iteration)
        int n2 = d2.y >> 5, c2 = d2.y & 31;
        int j2 = d2.x + (r16 < c2 ? r16 : c2 - 1);
        int s2 = csr_src[j2];
        float inv2 = inv_deg[n2];

        // T+3 desc
        int idx3 = idx2 + NSEQ;
        int2 d3 = tdesc[idx3 < nt ? idx3 : nt - 1];

        // ---- MFMA on tile T ----
        f32x4 cf[2], cs[2];
#pragma unroll
        for (int ctl = 0; ctl < 2; ctl++) {
            cf[ctl] = (f32x4){0.f, 0.f, 0.f, 0.f};
            cs[ctl] = (f32x4){0.f, 0.f, 0.f, 0.f};
        }
#pragma unroll
        for (int ctl = 0; ctl < 2; ctl++) {
            cf[ctl] = __builtin_amdgcn_mfma_f32_16x16x32_f16(cA0, Bf[0][ctl], cf[ctl], 0, 0, 0);
            cs[ctl] = __builtin_amdgcn_mfma_f32_16x16x32_f16(cA0, Bs[0][ctl], cs[ctl], 0, 0, 0);
            cf[ctl] = __builtin_amdgcn_mfma_f32_16x16x32_f16(cA1, Bf[1][ctl], cf[ctl], 0, 0, 0);
            cs[ctl] = __builtin_amdgcn_mfma_f32_16x16x32_f16(cA1, Bs[1][ctl], cs[ctl], 0, 0, 0);
            cf[ctl] = __builtin_amdgcn_mfma_f32_16x16x32_f16(cP2, Bf[2][ctl], cf[ctl], 0, 0, 0);
            cs[ctl] = __builtin_amdgcn_mfma_f32_16x16x32_f16(cP2, Bs[2][ctl], cs[ctl], 0, 0, 0);
            cf[ctl] = __builtin_amdgcn_mfma_f32_16x16x32_f16(cP3, Bf[3][ctl], cf[ctl], 0, 0, 0);
            cs[ctl] = __builtin_amdgcn_mfma_f32_16x16x32_f16(cP3, Bs[3][ctl], cs[ctl], 0, 0, 0);
            cf[ctl] = __builtin_amdgcn_mfma_f32_16x16x32_f16(cP4, Bf[4][ctl], cf[ctl], 0, 0, 0);
            cs[ctl] = __builtin_amdgcn_mfma_f32_16x16x32_f16(cP4, Bs[4][ctl], cs[ctl], 0, 0, 0);
        }

        // activation + per-tile reduce; C layout: col(lane&15)=chan, row(quad*4+rr)=edge
        float acc0 = 0.0f, acc1 = 0.0f;
#pragma unroll
        for (int ctl = 0; ctl < 2; ctl++) {
#pragma unroll
            for (int rr = 0; rr < 4; rr++) {
                float af = cf[ctl][rr] + biasf[ctl];
                float as = cs[ctl][rr] + biass[ctl];
                float sg = 1.0f / (1.0f + __expf(-af));
                float sp = fmaxf(as, 0.0f) + __logf(1.0f + __expf(-fabsf(as)));
                float msg = (quad * 4 + rr < c0) ? sg * sp : 0.0f;
                if (ctl == 0) acc0 += msg; else acc1 += msg;
            }
        }
        acc0 += __shfl_xor(acc0, 16);
        acc0 += __shfl_xor(acc0, 32);
        acc1 += __shfl_xor(acc1, 16);
        acc1 += __shfl_xor(acc1, 32);
        if (lane < 32) {
            float a = (lane < 16) ? acc0 : acc1;
            atomicAdd(&x[(size_t)n0 * GC + cthalf * 32 + lane], a * inv0);
        }

        idx += NSEQ;
        if (idx >= nt) break;
        // rotate pipeline
        cA0 = nA0; cA1 = nA1; cP2 = nP2; cP3 = nP3; cP4 = nP4;
        n0 = n1; c0 = c1; inv0 = inv1;
        n1 = n2; c1 = c2; j1 = j2; s1 = s2; inv1 = inv2;
        d2 = d3; idx2 = idx3;
    }
}

// ---------- K6: BN stats ----------
__global__ __launch_bounds__(256) void stats_kernel(const float* __restrict__ x, float* __restrict__ stats)
{
    const int lane = threadIdx.x & 63;
    const int wid = threadIdx.x >> 6;
    int w = blockIdx.x * 4 + wid;  // 0..1023
    float s1 = 0.0f, s2 = 0.0f;
    for (int n = w; n < N_NODES; n += 1024) {
        float v = x[(size_t)n * GC + lane];
        s1 += v;
        s2 = fmaf(v, v, s2);
    }
    __shared__ float rs1[4][64];
    __shared__ float rs2[4][64];
    rs1[wid][lane] = s1;
    rs2[wid][lane] = s2;
    __syncthreads();
    if (threadIdx.x < 64) {
        atomicAdd(&stats[lane], rs1[0][lane] + rs1[1][lane] + rs1[2][lane] + rs1[3][lane]);
    } else if (threadIdx.x < 128) {
        int c = threadIdx.x & 63;
        atomicAdd(&stats[64 + c], rs2[0][c] + rs2[1][c] + rs2[2][c] + rs2[3][c]);
    }
}

// ---------- K7: batchnorm apply (writes fp32 out and fp16 x16) ----------
__global__ __launch_bounds__(256) void bn_kernel(
    const float* __restrict__ xn, const float* __restrict__ stats,
    const float* __restrict__ gamma, const float* __restrict__ beta,
    float* __restrict__ out, _Float16* __restrict__ out16)
{
    int i = blockIdx.x * 256 + threadIdx.x;  // i < N*16
    int c4 = (i & 15) * 4;
    float4 v = ((const float4*)xn)[i];
    float vv[4] = {v.x, v.y, v.z, v.w};
    float o[4];
    const float invN = 1.0f / (float)N_NODES;
#pragma unroll
    for (int t = 0; t < 4; t++) {
        int c = c4 + t;
        float mu = stats[c] * invN;
        float var = stats[64 + c] * invN - mu * mu;
        float sc = gamma[c] * rsqrtf(var + BN_EPS);
        o[t] = (vv[t] - mu) * sc + beta[c];
    }
    ((float4*)out)[i] = make_float4(o[0], o[1], o[2], o[3]);
    half4 h = { (_Float16)o[0], (_Float16)o[1], (_Float16)o[2], (_Float16)o[3] };
    ((half4*)out16)[i] = h;
}

extern "C" void kernel_launch(void* const* d_in, const int* in_sizes, int n_in,
                              void* d_out, int out_size, void* d_ws, size_t ws_size,
                              hipStream_t stream)
{
    const int* atom_types = (const int*)d_in[0];
    const float* pos = (const float*)d_in[1];
    const int* edge_index = (const int*)d_in[2];
    const float* emb = (const float*)d_in[3];
    const float* pre_W = (const float*)d_in[4];
    const float* pre_b = (const float*)d_in[5];
    const float* Wf = (const float*)d_in[6];
    const float* bf = (const float*)d_in[7];
    const float* Ws = (const float*)d_in[8];
    const float* bs = (const float*)d_in[9];
    const float* gamma = (const float*)d_in[10];
    const float* beta = (const float*)d_in[11];
    const float* means = (const float*)d_in[12];
    const float* betas = (const float*)d_in[13];

    char* base = (char*)d_ws;
    char* p = base;
    auto alloc = [&](size_t bytes) -> char* {
        char* r = p;
        p += (bytes + 255) & ~(size_t)255;
        return r;
    };
    unsigned int* ea = (unsigned int*)alloc((size_t)N_EDGES * RBF * 2);   // 76.8 MB fp16
    float* x = (float*)alloc((size_t)N_NODES * GC * 4);                   // 25.6 MB
    _Float16* x16 = (_Float16*)alloc((size_t)N_NODES * GC * 2);           // 12.8 MB
    int* csr_src = (int*)alloc((size_t)N_EDGES * 4);                      // 4.8 MB
    int2* tdesc = (int2*)alloc((size_t)NTILE_MAX * 8);                    // 1.76 MB
    int* row_st = (int*)alloc((size_t)(N_NODES + 1) * 4);
    float* inv_deg = (float*)alloc((size_t)N_NODES * 4);
    float* T = (float*)alloc((size_t)NATOM * GC * 4);
    int* bsums = (int*)alloc(512 * 4);
    int* boffs = (int*)alloc(512 * 4);
    const size_t ZR_INTS = (size_t)2 * N_NODES + 128 * NLAYERS + 64;
    char* zr = alloc(ZR_INTS * 4);
    int* deg = (int*)zr;
    int* cursor = deg + N_NODES;
    float* stats = (float*)(cursor + N_NODES);
    int* tcount = (int*)(stats + 128 * NLAYERS);

    if ((size_t)(p - base) > ws_size) return;  // diagnostic bail: leaves poison in d_out

    hipMemsetAsync(zr, 0, ZR_INTS * 4, stream);

    const int EG = (N_EDGES + 255) / 256;
    deg_kernel<<<EG, 256, 0, stream>>>(edge_index, deg);
    scan_a_kernel<<<391, 256, 0, stream>>>(deg, bsums);
    scan_b_kernel<<<1, 512, 0, stream>>>(bsums, boffs);
    scan_c_kernel<<<391, 256, 0, stream>>>(deg, boffs, row_st, inv_deg);
    scatter_rbf_kernel<<<EG, 256, 0, stream>>>(edge_index, pos, row_st, cursor,
                                               means, betas, csr_src, ea);
    tile_build_kernel<<<391, 256, 0, stream>>>(row_st, tdesc, tcount);
    atom_table_kernel<<<NATOM, 64, 0, stream>>>(emb, pre_W, pre_b, T);
    xinit_kernel<<<N_NODES * 16 / 256, 256, 0, stream>>>(atom_types, T, x, x16);

    for (int l = 0; l < NLAYERS; l++) {
        const float* Wfl = Wf + (size_t)l * 160 * GC;
        const float* Wsl = Ws + (size_t)l * 160 * GC;
        tile_mfma_kernel<<<TILE_GRID, 256, 0, stream>>>(
            x16, (const _Float16*)ea, csr_src, tdesc, tcount, inv_deg,
            Wfl, Wsl, bf + l * GC, bs + l * GC, x);
        stats_kernel<<<256, 256, 0, stream>>>(x, stats + l * 128);
        bn_kernel<<<N_NODES * 16 / 256, 256, 0, stream>>>(
            x, stats + l * 128, gamma + l * GC, beta + l * GC,
            (l == NLAYERS - 1) ? (float*)d_out : x, x16);
    }
}

// Round 7
// 1108.984 us; speedup vs baseline: 1.6112x; 1.0135x over previous
//
#include <hip/hip_runtime.h>
#include <math.h>

#define N_NODES 100000
#define N_EDGES 1200000
#define GC 64
#define RBF 32
#define NLAYERS 4
#define NF 92
#define NATOM 100
#define BN_EPS 1e-5f
#define TILE_GRID 1024
#define NTILE_MAX 176000   // worst case N + E/16 = 175k

typedef _Float16 half8 __attribute__((ext_vector_type(8)));
typedef _Float16 half4 __attribute__((ext_vector_type(4)));
typedef float f32x4 __attribute__((ext_vector_type(4)));

// ---------- K1: degree histogram ----------
__global__ __launch_bounds__(256) void deg_kernel(
    const int* __restrict__ ei, int* __restrict__ deg)
{
    int e = blockIdx.x * 256 + threadIdx.x;
    if (e >= N_EDGES) return;
    atomicAdd(&deg[ei[N_EDGES + e]], 1);
}

// ---------- scan ----------
__global__ __launch_bounds__(256) void scan_a_kernel(const int* __restrict__ deg, int* __restrict__ bsums)
{
    __shared__ int sm[256];
    int tid = threadIdx.x;
    int i = blockIdx.x * 256 + tid;
    int v = (i < N_NODES) ? deg[i] : 0;
    sm[tid] = v;
    __syncthreads();
    for (int s = 128; s > 0; s >>= 1) {
        if (tid < s) sm[tid] += sm[tid + s];
        __syncthreads();
    }
    if (tid == 0) bsums[blockIdx.x] = sm[0];
}

__global__ __launch_bounds__(512) void scan_b_kernel(const int* __restrict__ bsums, int* __restrict__ boffs)
{
    __shared__ int sm[512];
    int tid = threadIdx.x;
    int v = (tid < 391) ? bsums[tid] : 0;
    sm[tid] = v;
    __syncthreads();
    for (int off = 1; off < 512; off <<= 1) {
        int t = (tid >= off) ? sm[tid - off] : 0;
        __syncthreads();
        sm[tid] += t;
        __syncthreads();
    }
    boffs[tid] = (tid == 0) ? 0 : sm[tid - 1];
}

__global__ __launch_bounds__(256) void scan_c_kernel(
    const int* __restrict__ deg, const int* __restrict__ boffs,
    int* __restrict__ row_st, float* __restrict__ inv_deg)
{
    __shared__ int sm[256];
    int tid = threadIdx.x;
    int i = blockIdx.x * 256 + tid;
    int v = (i < N_NODES) ? deg[i] : 0;
    sm[tid] = v;
    __syncthreads();
    for (int off = 1; off < 256; off <<= 1) {
        int t = (tid >= off) ? sm[tid - off] : 0;
        __syncthreads();
        sm[tid] += t;
        __syncthreads();
    }
    if (i <= N_NODES) row_st[i] = boffs[blockIdx.x] + sm[tid] - v;  // exclusive
    if (i < N_NODES) inv_deg[i] = (v > 0) ? (1.0f / (float)v) : 0.0f;
}

// ---------- K2: scatter edges into CSR order + fused RBF (fp16) ----------
__global__ __launch_bounds__(256) void scatter_rbf_kernel(
    const int* __restrict__ ei, const float* __restrict__ pos,
    const int* __restrict__ row_st, int* __restrict__ cursor,
    const float* __restrict__ means, const float* __restrict__ betas,
    int* __restrict__ csr_src, unsigned int* __restrict__ ea)
{
    int e = blockIdx.x * 256 + threadIdx.x;
    if (e >= N_EDGES) return;
    int s = ei[e];
    int d = ei[N_EDGES + e];
    float dx = pos[s * 3 + 0] - pos[d * 3 + 0];
    float dy = pos[s * 3 + 1] - pos[d * 3 + 1];
    float dz = pos[s * 3 + 2] - pos[d * 3 + 2];
    float dist = sqrtf(dx * dx + dy * dy + dz * dz + 1e-12f);

    int p = atomicAdd(&cursor[d], 1);
    int idx = row_st[d] + p;
    csr_src[idx] = s;

    float cut = 0.0f;
    if (dist < 5.0f) cut = 0.5f * (__cosf(dist * 0.6283185307179586f) + 1.0f);
    float ex = __expf(-dist);
    union { _Float16 h[32]; uint4 u[4]; } pk;
#pragma unroll
    for (int k = 0; k < 32; k++) {
        float v = ex - means[k];
        pk.h[k] = (_Float16)(cut * __expf(-betas[k] * v * v));
    }
    uint4* op = (uint4*)(ea + (size_t)idx * 16);
    op[0] = pk.u[0];
    op[1] = pk.u[1];
    op[2] = pk.u[2];
    op[3] = pk.u[3];
}

// ---------- K3: flat tile-descriptor list ----------
__global__ __launch_bounds__(256) void tile_build_kernel(
    const int* __restrict__ row_st, int2* __restrict__ tdesc, int* __restrict__ tcount)
{
    int n = blockIdx.x * 256 + threadIdx.x;
    if (n >= N_NODES) return;
    int row = row_st[n];
    int dg = row_st[n + 1] - row;
    int tiles = (dg + 15) >> 4;
    if (tiles == 0) return;
    int base = atomicAdd(tcount, tiles);
    for (int t = 0; t < tiles; t++) {
        int cnt = dg - 16 * t;
        if (cnt > 16) cnt = 16;
        tdesc[base + t] = make_int2(row + 16 * t, (n << 5) | cnt);
    }
}

// ---------- K4a: per-atom-type pre-layer table ----------
__global__ __launch_bounds__(64) void atom_table_kernel(
    const float* __restrict__ emb, const float* __restrict__ pre_W,
    const float* __restrict__ pre_b, float* __restrict__ T)
{
    int a = blockIdx.x;
    int c = threadIdx.x;
    float acc = pre_b[c];
    for (int k = 0; k < NF; k++) acc = fmaf(emb[a * NF + k], pre_W[k * GC + c], acc);
    T[a * GC + c] = fmaxf(acc, 0.0f);
}

// ---------- K4b: broadcast table to nodes ----------
__global__ __launch_bounds__(256) void xinit_kernel(
    const int* __restrict__ atom_types, const float* __restrict__ T,
    float* __restrict__ x, _Float16* __restrict__ x16)
{
    int i = blockIdx.x * 256 + threadIdx.x;  // i < N*16
    int n = i >> 4;
    int a = atom_types[n];
    float4 v = ((const float4*)T)[a * 16 + (i & 15)];
    ((float4*)x)[i] = v;
    half4 h = { (_Float16)v.x, (_Float16)v.y, (_Float16)v.z, (_Float16)v.w };
    ((half4*)x16)[i] = h;
}

// ---------- K_proj: dst-projections Pf/Ps[n][c] = sum_k x16[n][k] * W[k][c] ----------
// Weights as MFMA A-operand (M=chans), nodes as B-operand (N=nodes). Bias folded in edge kernel.
__global__ __launch_bounds__(256) void proj_kernel(
    const _Float16* __restrict__ x16,
    const float* __restrict__ Wf, const float* __restrict__ Ws,   // rows 0..63
    _Float16* __restrict__ Pf, _Float16* __restrict__ Ps)
{
    const int lane = threadIdx.x & 63;
    const int wid = threadIdx.x >> 6;
    const int quad = lane >> 4;
    const int r16 = lane & 15;
    const int wgid = blockIdx.x * 4 + wid;
    const int tile = wgid >> 1;
    const int cb = (wgid & 1) * 32;
    const int nb = tile * 16;

    half8 Af[2][2], As[2][2];  // [kt][sub]: A[m=chan][k]
#pragma unroll
    for (int kt = 0; kt < 2; kt++) {
#pragma unroll
        for (int sub = 0; sub < 2; sub++) {
            int chan = cb + sub * 16 + r16;
            half8 a, b;
#pragma unroll
            for (int j = 0; j < 8; j++) {
                int k = kt * 32 + quad * 8 + j;
                a[j] = (_Float16)Wf[k * GC + chan];
                b[j] = (_Float16)Ws[k * GC + chan];
            }
            Af[kt][sub] = a;
            As[kt][sub] = b;
        }
    }
    half8 Bn[2];
    Bn[0] = *(const half8*)(x16 + (size_t)(nb + r16) * GC + quad * 8);
    Bn[1] = *(const half8*)(x16 + (size_t)(nb + r16) * GC + 32 + quad * 8);

    f32x4 accf[2], accs[2];
#pragma unroll
    for (int sub = 0; sub < 2; sub++) {
        accf[sub] = (f32x4){0.f, 0.f, 0.f, 0.f};
        accs[sub] = (f32x4){0.f, 0.f, 0.f, 0.f};
    }
#pragma unroll
    for (int kt = 0; kt < 2; kt++) {
#pragma unroll
        for (int sub = 0; sub < 2; sub++) {
            accf[sub] = __builtin_amdgcn_mfma_f32_16x16x32_f16(Af[kt][sub], Bn[kt], accf[sub], 0, 0, 0);
            accs[sub] = __builtin_amdgcn_mfma_f32_16x16x32_f16(As[kt][sub], Bn[kt], accs[sub], 0, 0, 0);
        }
    }
    // C: col=lane&15 -> node, row=quad*4+rr -> chan within subtile
    int node = nb + r16;
#pragma unroll
    for (int sub = 0; sub < 2; sub++) {
        half4 hf = { (_Float16)accf[sub][0], (_Float16)accf[sub][1],
                     (_Float16)accf[sub][2], (_Float16)accf[sub][3] };
        half4 hs = { (_Float16)accs[sub][0], (_Float16)accs[sub][1],
                     (_Float16)accs[sub][2], (_Float16)accs[sub][3] };
        *(half4*)(Pf + (size_t)node * GC + cb + sub * 16 + quad * 4) = hf;
        *(half4*)(Ps + (size_t)node * GC + cb + sub * 16 + quad * 4) = hs;
    }
}

// ---------- K5: flat-tile MFMA CGConv layer ----------
// src part: 2 fp16 ktiles (x16[src]); ea part: 1 fp16 ktile; dst part folded via Pf/Ps acc-init.
__global__ __launch_bounds__(256, 4) void tile_mfma_kernel(
    const _Float16* __restrict__ x16, const _Float16* __restrict__ ea,
    const int* __restrict__ csr_src, const int2* __restrict__ tdesc,
    const int* __restrict__ tcount, const float* __restrict__ inv_deg,
    const _Float16* __restrict__ Pf, const _Float16* __restrict__ Ps,
    const float* __restrict__ Wf, const float* __restrict__ Ws,   // [160][64]
    const float* __restrict__ bfv, const float* __restrict__ bsv, // [64]
    float* __restrict__ x)
{
    const int lane = threadIdx.x & 63;
    const int wid = threadIdx.x >> 6;
    const int quad = lane >> 4;
    const int r16 = lane & 15;

    const int wgid = blockIdx.x * 4 + wid;
    const int cthalf = wgid & 1;
    const int seq = wgid >> 1;
    const int NSEQ = TILE_GRID * 2;
    const int cb = cthalf * 32;

    // fp16 B fragments: kt=0,1 -> W rows 64..127 (src), kt=2 -> rows 128..159 (ea)
    half8 Bf[3][2], Bs[3][2];
#pragma unroll
    for (int kt = 0; kt < 3; kt++) {
#pragma unroll
        for (int ctl = 0; ctl < 2; ctl++) {
            int col = cb + ctl * 16 + r16;
            half8 bh, sh;
#pragma unroll
            for (int j = 0; j < 8; j++) {
                int k = 64 + kt * 32 + quad * 8 + j;
                bh[j] = (_Float16)Wf[k * GC + col];
                sh[j] = (_Float16)Ws[k * GC + col];
            }
            Bf[kt][ctl] = bh;
            Bs[kt][ctl] = sh;
        }
    }
    float biasf[2], biass[2];
#pragma unroll
    for (int ctl = 0; ctl < 2; ctl++) {
        int col = cb + ctl * 16 + r16;
        biasf[ctl] = bfv[col];
        biass[ctl] = bsv[col];
    }

    const int nt = tcount[0];
    if (seq >= nt) return;

    // ---- prologue ----
    int idx = seq;
    int2 d0 = tdesc[idx];
    int n0 = d0.y >> 5, c0 = d0.y & 31;
    int j0 = d0.x + (r16 < c0 ? r16 : c0 - 1);
    float inv0 = inv_deg[n0];
    int s0 = csr_src[j0];
    half8 cS0 = *(const half8*)(x16 + (size_t)s0 * GC + quad * 8);
    half8 cS1 = *(const half8*)(x16 + (size_t)s0 * GC + 32 + quad * 8);
    half8 cE  = *(const half8*)(ea + (size_t)j0 * RBF + quad * 8);
    float pf0[2], ps0[2];
#pragma unroll
    for (int ctl = 0; ctl < 2; ctl++) {
        pf0[ctl] = (float)Pf[(size_t)n0 * GC + cb + ctl * 16 + r16];
        ps0[ctl] = (float)Ps[(size_t)n0 * GC + cb + ctl * 16 + r16];
    }

    int idx1 = idx + NSEQ;
    int2 d1 = tdesc[idx1 < nt ? idx1 : nt - 1];
    int n1 = d1.y >> 5, c1 = d1.y & 31;
    int j1 = d1.x + (r16 < c1 ? r16 : c1 - 1);
    int s1 = csr_src[j1];
    float inv1 = inv_deg[n1];

    int idx2 = idx1 + NSEQ;
    int2 d2 = tdesc[idx2 < nt ? idx2 : nt - 1];

    while (true) {
        // issue T+1 fragment + P loads
        half8 nS0 = *(const half8*)(x16 + (size_t)s1 * GC + quad * 8);
        half8 nS1 = *(const half8*)(x16 + (size_t)s1 * GC + 32 + quad * 8);
        half8 nE  = *(const half8*)(ea + (size_t)j1 * RBF + quad * 8);
        float npf[2], nps[2];
#pragma unroll
        for (int ctl = 0; ctl < 2; ctl++) {
            npf[ctl] = (float)Pf[(size_t)n1 * GC + cb + ctl * 16 + r16];
            nps[ctl] = (float)Ps[(size_t)n1 * GC + cb + ctl * 16 + r16];
        }

        // T+2 meta
        int n2 = d2.y >> 5, c2 = d2.y & 31;
        int j2 = d2.x + (r16 < c2 ? r16 : c2 - 1);
        int s2 = csr_src[j2];
        float inv2 = inv_deg[n2];

        // T+3 desc
        int idx3 = idx2 + NSEQ;
        int2 d3 = tdesc[idx3 < nt ? idx3 : nt - 1];

        // ---- MFMA on tile T (acc init = dst-proj + bias, broadcast across edge rows) ----
        f32x4 cf[2], cs[2];
#pragma unroll
        for (int ctl = 0; ctl < 2; ctl++) {
            float fi = pf0[ctl] + biasf[ctl];
            float si = ps0[ctl] + biass[ctl];
            cf[ctl] = (f32x4){fi, fi, fi, fi};
            cs[ctl] = (f32x4){si, si, si, si};
        }
#pragma unroll
        for (int ctl = 0; ctl < 2; ctl++) {
            cf[ctl] = __builtin_amdgcn_mfma_f32_16x16x32_f16(cS0, Bf[0][ctl], cf[ctl], 0, 0, 0);
            cs[ctl] = __builtin_amdgcn_mfma_f32_16x16x32_f16(cS0, Bs[0][ctl], cs[ctl], 0, 0, 0);
            cf[ctl] = __builtin_amdgcn_mfma_f32_16x16x32_f16(cS1, Bf[1][ctl], cf[ctl], 0, 0, 0);
            cs[ctl] = __builtin_amdgcn_mfma_f32_16x16x32_f16(cS1, Bs[1][ctl], cs[ctl], 0, 0, 0);
            cf[ctl] = __builtin_amdgcn_mfma_f32_16x16x32_f16(cE,  Bf[2][ctl], cf[ctl], 0, 0, 0);
            cs[ctl] = __builtin_amdgcn_mfma_f32_16x16x32_f16(cE,  Bs[2][ctl], cs[ctl], 0, 0, 0);
        }

        // activation + reduce; C layout: col(lane&15)=chan, row(quad*4+rr)=edge
        float acc0 = 0.0f, acc1 = 0.0f;
#pragma unroll
        for (int ctl = 0; ctl < 2; ctl++) {
#pragma unroll
            for (int rr = 0; rr < 4; rr++) {
                float af = cf[ctl][rr];
                float as = cs[ctl][rr];
                float sg = 1.0f / (1.0f + __expf(-af));
                float sp = fmaxf(as, 0.0f) + __logf(1.0f + __expf(-fabsf(as)));
                float msg = (quad * 4 + rr < c0) ? sg * sp : 0.0f;
                if (ctl == 0) acc0 += msg; else acc1 += msg;
            }
        }
        acc0 += __shfl_xor(acc0, 16);
        acc0 += __shfl_xor(acc0, 32);
        acc1 += __shfl_xor(acc1, 16);
        acc1 += __shfl_xor(acc1, 32);
        if (lane < 32) {
            float a = (lane < 16) ? acc0 : acc1;
            atomicAdd(&x[(size_t)n0 * GC + cb + lane], a * inv0);
        }

        idx += NSEQ;
        if (idx >= nt) break;
        // rotate pipeline
        cS0 = nS0; cS1 = nS1; cE = nE;
        pf0[0] = npf[0]; pf0[1] = npf[1]; ps0[0] = nps[0]; ps0[1] = nps[1];
        n0 = n1; c0 = c1; inv0 = inv1;
        n1 = n2; c1 = c2; j1 = j2; s1 = s2; inv1 = inv2;
        d2 = d3; idx2 = idx3;
    }
}

// ---------- K6: BN stats ----------
__global__ __launch_bounds__(256) void stats_kernel(const float* __restrict__ x, float* __restrict__ stats)
{
    const int lane = threadIdx.x & 63;
    const int wid = threadIdx.x >> 6;
    int w = blockIdx.x * 4 + wid;
    float s1 = 0.0f, s2 = 0.0f;
    for (int n = w; n < N_NODES; n += 1024) {
        float v = x[(size_t)n * GC + lane];
        s1 += v;
        s2 = fmaf(v, v, s2);
    }
    __shared__ float rs1[4][64];
    __shared__ float rs2[4][64];
    rs1[wid][lane] = s1;
    rs2[wid][lane] = s2;
    __syncthreads();
    if (threadIdx.x < 64) {
        atomicAdd(&stats[lane], rs1[0][lane] + rs1[1][lane] + rs1[2][lane] + rs1[3][lane]);
    } else if (threadIdx.x < 128) {
        int c = threadIdx.x & 63;
        atomicAdd(&stats[64 + c], rs2[0][c] + rs2[1][c] + rs2[2][c] + rs2[3][c]);
    }
}

// ---------- K7: batchnorm apply ----------
__global__ __launch_bounds__(256) void bn_kernel(
    const float* __restrict__ xn, const float* __restrict__ stats,
    const float* __restrict__ gamma, const float* __restrict__ beta,
    float* __restrict__ out, _Float16* __restrict__ out16)
{
    int i = blockIdx.x * 256 + threadIdx.x;
    int c4 = (i & 15) * 4;
    float4 v = ((const float4*)xn)[i];
    float vv[4] = {v.x, v.y, v.z, v.w};
    float o[4];
    const float invN = 1.0f / (float)N_NODES;
#pragma unroll
    for (int t = 0; t < 4; t++) {
        int c = c4 + t;
        float mu = stats[c] * invN;
        float var = stats[64 + c] * invN - mu * mu;
        float sc = gamma[c] * rsqrtf(var + BN_EPS);
        o[t] = (vv[t] - mu) * sc + beta[c];
    }
    ((float4*)out)[i] = make_float4(o[0], o[1], o[2], o[3]);
    half4 h = { (_Float16)o[0], (_Float16)o[1], (_Float16)o[2], (_Float16)o[3] };
    ((half4*)out16)[i] = h;
}

extern "C" void kernel_launch(void* const* d_in, const int* in_sizes, int n_in,
                              void* d_out, int out_size, void* d_ws, size_t ws_size,
                              hipStream_t stream)
{
    const int* atom_types = (const int*)d_in[0];
    const float* pos = (const float*)d_in[1];
    const int* edge_index = (const int*)d_in[2];
    const float* emb = (const float*)d_in[3];
    const float* pre_W = (const float*)d_in[4];
    const float* pre_b = (const float*)d_in[5];
    const float* Wf = (const float*)d_in[6];
    const float* bf = (const float*)d_in[7];
    const float* Ws = (const float*)d_in[8];
    const float* bs = (const float*)d_in[9];
    const float* gamma = (const float*)d_in[10];
    const float* beta = (const float*)d_in[11];
    const float* means = (const float*)d_in[12];
    const float* betas = (const float*)d_in[13];

    char* base = (char*)d_ws;
    char* p = base;
    auto alloc = [&](size_t bytes) -> char* {
        char* r = p;
        p += (bytes + 255) & ~(size_t)255;
        return r;
    };
    unsigned int* ea = (unsigned int*)alloc((size_t)N_EDGES * RBF * 2);   // 76.8 MB fp16
    float* x = (float*)alloc((size_t)N_NODES * GC * 4);                   // 25.6 MB
    _Float16* x16 = (_Float16*)alloc((size_t)N_NODES * GC * 2);           // 12.8 MB
    _Float16* Pf = (_Float16*)alloc((size_t)N_NODES * GC * 2);            // 12.8 MB
    _Float16* Ps = (_Float16*)alloc((size_t)N_NODES * GC * 2);            // 12.8 MB
    int* csr_src = (int*)alloc((size_t)N_EDGES * 4);                      // 4.8 MB
    int2* tdesc = (int2*)alloc((size_t)NTILE_MAX * 8);                    // 1.4 MB
    int* row_st = (int*)alloc((size_t)(N_NODES + 1) * 4);
    float* inv_deg = (float*)alloc((size_t)N_NODES * 4);
    float* T = (float*)alloc((size_t)NATOM * GC * 4);
    int* bsums = (int*)alloc(512 * 4);
    int* boffs = (int*)alloc(512 * 4);
    const size_t ZR_INTS = (size_t)2 * N_NODES + 128 * NLAYERS + 64;
    char* zr = alloc(ZR_INTS * 4);
    int* deg = (int*)zr;
    int* cursor = deg + N_NODES;
    float* stats = (float*)(cursor + N_NODES);
    int* tcount = (int*)(stats + 128 * NLAYERS);

    if ((size_t)(p - base) > ws_size) return;  // diagnostic bail

    hipMemsetAsync(zr, 0, ZR_INTS * 4, stream);

    const int EG = (N_EDGES + 255) / 256;
    deg_kernel<<<EG, 256, 0, stream>>>(edge_index, deg);
    scan_a_kernel<<<391, 256, 0, stream>>>(deg, bsums);
    scan_b_kernel<<<1, 512, 0, stream>>>(bsums, boffs);
    scan_c_kernel<<<391, 256, 0, stream>>>(deg, boffs, row_st, inv_deg);
    scatter_rbf_kernel<<<EG, 256, 0, stream>>>(edge_index, pos, row_st, cursor,
                                               means, betas, csr_src, ea);
    tile_build_kernel<<<391, 256, 0, stream>>>(row_st, tdesc, tcount);
    atom_table_kernel<<<NATOM, 64, 0, stream>>>(emb, pre_W, pre_b, T);
    xinit_kernel<<<N_NODES * 16 / 256, 256, 0, stream>>>(atom_types, T, x, x16);

    for (int l = 0; l < NLAYERS; l++) {
        const float* Wfl = Wf + (size_t)l * 160 * GC;
        const float* Wsl = Ws + (size_t)l * 160 * GC;
        proj_kernel<<<N_NODES / 16 / 2, 256, 0, stream>>>(x16, Wfl, Wsl, Pf, Ps);
        tile_mfma_kernel<<<TILE_GRID, 256, 0, stream>>>(
            x16, (const _Float16*)ea, csr_src, tdesc, tcount, inv_deg, Pf, Ps,
            Wfl, Wsl, bf + l * GC, bs + l * GC, x);
        stats_kernel<<<256, 256, 0, stream>>>(x, stats + l * 128);
        bn_kernel<<<N_NODES * 16 / 256, 256, 0, stream>>>(
            x, stats + l * 128, gamma + l * GC, beta + l * GC,
            (l == NLAYERS - 1) ? (float*)d_out : x, x16);
    }
}

// Round 8
// 1037.336 us; speedup vs baseline: 1.7225x; 1.0691x over previous
//
#include <hip/hip_runtime.h>
#include <math.h>

#define N_NODES 100000
#define N_EDGES 1200000
#define GC 64
#define RBF 32
#define NLAYERS 4
#define NF 92
#define NATOM 100
#define BN_EPS 1e-5f
#define TILE_GRID 2048
#define NTILE_MAX 176000   // worst case N + E/16 = 175k

typedef _Float16 half8 __attribute__((ext_vector_type(8)));
typedef _Float16 half4 __attribute__((ext_vector_type(4)));
typedef _Float16 half2v __attribute__((ext_vector_type(2)));
typedef float f32x4 __attribute__((ext_vector_type(4)));
union U32H2 { unsigned int u; half2v h; };

// ---------- K1: degree histogram ----------
__global__ __launch_bounds__(256) void deg_kernel(
    const int* __restrict__ ei, int* __restrict__ deg)
{
    int e = blockIdx.x * 256 + threadIdx.x;
    if (e >= N_EDGES) return;
    atomicAdd(&deg[ei[N_EDGES + e]], 1);
}

// ---------- scan ----------
__global__ __launch_bounds__(256) void scan_a_kernel(const int* __restrict__ deg, int* __restrict__ bsums)
{
    __shared__ int sm[256];
    int tid = threadIdx.x;
    int i = blockIdx.x * 256 + tid;
    int v = (i < N_NODES) ? deg[i] : 0;
    sm[tid] = v;
    __syncthreads();
    for (int s = 128; s > 0; s >>= 1) {
        if (tid < s) sm[tid] += sm[tid + s];
        __syncthreads();
    }
    if (tid == 0) bsums[blockIdx.x] = sm[0];
}

__global__ __launch_bounds__(512) void scan_b_kernel(const int* __restrict__ bsums, int* __restrict__ boffs)
{
    __shared__ int sm[512];
    int tid = threadIdx.x;
    int v = (tid < 391) ? bsums[tid] : 0;
    sm[tid] = v;
    __syncthreads();
    for (int off = 1; off < 512; off <<= 1) {
        int t = (tid >= off) ? sm[tid - off] : 0;
        __syncthreads();
        sm[tid] += t;
        __syncthreads();
    }
    boffs[tid] = (tid == 0) ? 0 : sm[tid - 1];
}

__global__ __launch_bounds__(256) void scan_c_kernel(
    const int* __restrict__ deg, const int* __restrict__ boffs,
    int* __restrict__ row_st, float* __restrict__ inv_deg)
{
    __shared__ int sm[256];
    int tid = threadIdx.x;
    int i = blockIdx.x * 256 + tid;
    int v = (i < N_NODES) ? deg[i] : 0;
    sm[tid] = v;
    __syncthreads();
    for (int off = 1; off < 256; off <<= 1) {
        int t = (tid >= off) ? sm[tid - off] : 0;
        __syncthreads();
        sm[tid] += t;
        __syncthreads();
    }
    if (i <= N_NODES) row_st[i] = boffs[blockIdx.x] + sm[tid] - v;  // exclusive
    if (i < N_NODES) inv_deg[i] = (v > 0) ? (1.0f / (float)v) : 0.0f;
}

// ---------- K2: scatter edges into CSR order + fused RBF (fp16) ----------
__global__ __launch_bounds__(256) void scatter_rbf_kernel(
    const int* __restrict__ ei, const float* __restrict__ pos,
    const int* __restrict__ row_st, int* __restrict__ cursor,
    const float* __restrict__ means, const float* __restrict__ betas,
    int* __restrict__ csr_src, unsigned int* __restrict__ ea)
{
    int e = blockIdx.x * 256 + threadIdx.x;
    if (e >= N_EDGES) return;
    int s = ei[e];
    int d = ei[N_EDGES + e];
    float dx = pos[s * 3 + 0] - pos[d * 3 + 0];
    float dy = pos[s * 3 + 1] - pos[d * 3 + 1];
    float dz = pos[s * 3 + 2] - pos[d * 3 + 2];
    float dist = sqrtf(dx * dx + dy * dy + dz * dz + 1e-12f);

    int p = atomicAdd(&cursor[d], 1);
    int idx = row_st[d] + p;
    csr_src[idx] = s;

    float cut = 0.0f;
    if (dist < 5.0f) cut = 0.5f * (__cosf(dist * 0.6283185307179586f) + 1.0f);
    float ex = __expf(-dist);
    union { _Float16 h[32]; uint4 u[4]; } pk;
#pragma unroll
    for (int k = 0; k < 32; k++) {
        float v = ex - means[k];
        pk.h[k] = (_Float16)(cut * __expf(-betas[k] * v * v));
    }
    uint4* op = (uint4*)(ea + (size_t)idx * 16);
    op[0] = pk.u[0];
    op[1] = pk.u[1];
    op[2] = pk.u[2];
    op[3] = pk.u[3];
}

// ---------- K3: flat tile-descriptor list ----------
__global__ __launch_bounds__(256) void tile_build_kernel(
    const int* __restrict__ row_st, int2* __restrict__ tdesc, int* __restrict__ tcount)
{
    int n = blockIdx.x * 256 + threadIdx.x;
    if (n >= N_NODES) return;
    int row = row_st[n];
    int dg = row_st[n + 1] - row;
    int tiles = (dg + 15) >> 4;
    if (tiles == 0) return;
    int base = atomicAdd(tcount, tiles);
    for (int t = 0; t < tiles; t++) {
        int cnt = dg - 16 * t;
        if (cnt > 16) cnt = 16;
        tdesc[base + t] = make_int2(row + 16 * t, (n << 5) | cnt);
    }
}

// ---------- K4a: per-atom-type pre-layer table ----------
__global__ __launch_bounds__(64) void atom_table_kernel(
    const float* __restrict__ emb, const float* __restrict__ pre_W,
    const float* __restrict__ pre_b, float* __restrict__ T)
{
    int a = blockIdx.x;
    int c = threadIdx.x;
    float acc = pre_b[c];
    for (int k = 0; k < NF; k++) acc = fmaf(emb[a * NF + k], pre_W[k * GC + c], acc);
    T[a * GC + c] = fmaxf(acc, 0.0f);
}

// ---------- K4b: broadcast table to nodes ----------
__global__ __launch_bounds__(256) void xinit_kernel(
    const int* __restrict__ atom_types, const float* __restrict__ T,
    float* __restrict__ x, _Float16* __restrict__ x16)
{
    int i = blockIdx.x * 256 + threadIdx.x;  // i < N*16
    int n = i >> 4;
    int a = atom_types[n];
    float4 v = ((const float4*)T)[a * 16 + (i & 15)];
    ((float4*)x)[i] = v;
    half4 h = { (_Float16)v.x, (_Float16)v.y, (_Float16)v.z, (_Float16)v.w };
    ((half4*)x16)[i] = h;
}

// ---------- shared MFMA proj body: P2[n][c] = {f,s} interleaved half2 ----------
// A = weights (M=16 chans per sub), B = 16 nodes' features. C: col=node, row=chan.
static __device__ __forceinline__ void proj_mfma(
    const float* __restrict__ Wf, const float* __restrict__ Ws,
    const half8 Bn[2], int cb, int node, half2v* __restrict__ P2)
{
    half8 Af[2][2], As[2][2];
    const int lane = threadIdx.x & 63;
    const int quad = lane >> 4;
    const int r16 = lane & 15;
#pragma unroll
    for (int kt = 0; kt < 2; kt++) {
#pragma unroll
        for (int sub = 0; sub < 2; sub++) {
            int chan = cb + sub * 16 + r16;
            half8 a, b;
#pragma unroll
            for (int j = 0; j < 8; j++) {
                int k = kt * 32 + quad * 8 + j;
                a[j] = (_Float16)Wf[k * GC + chan];
                b[j] = (_Float16)Ws[k * GC + chan];
            }
            Af[kt][sub] = a;
            As[kt][sub] = b;
        }
    }
    f32x4 accf[2], accs[2];
#pragma unroll
    for (int sub = 0; sub < 2; sub++) {
        accf[sub] = (f32x4){0.f, 0.f, 0.f, 0.f};
        accs[sub] = (f32x4){0.f, 0.f, 0.f, 0.f};
    }
#pragma unroll
    for (int kt = 0; kt < 2; kt++) {
#pragma unroll
        for (int sub = 0; sub < 2; sub++) {
            accf[sub] = __builtin_amdgcn_mfma_f32_16x16x32_f16(Af[kt][sub], Bn[kt], accf[sub], 0, 0, 0);
            accs[sub] = __builtin_amdgcn_mfma_f32_16x16x32_f16(As[kt][sub], Bn[kt], accs[sub], 0, 0, 0);
        }
    }
#pragma unroll
    for (int sub = 0; sub < 2; sub++) {
        half8 h = { (_Float16)accf[sub][0], (_Float16)accs[sub][0],
                    (_Float16)accf[sub][1], (_Float16)accs[sub][1],
                    (_Float16)accf[sub][2], (_Float16)accs[sub][2],
                    (_Float16)accf[sub][3], (_Float16)accs[sub][3] };
        *(half8*)(P2 + (size_t)node * GC + cb + sub * 16 + quad * 4) = h;
    }
}

// ---------- K_proj0: standalone proj (layer 0, x16 from xinit) ----------
__global__ __launch_bounds__(256) void proj_kernel(
    const _Float16* __restrict__ x16,
    const float* __restrict__ Wf, const float* __restrict__ Ws,
    half2v* __restrict__ P2)
{
    const int lane = threadIdx.x & 63;
    const int wid = threadIdx.x >> 6;
    const int quad = lane >> 4;
    const int r16 = lane & 15;
    const int wgid = blockIdx.x * 4 + wid;
    const int cb = (wgid & 1) * 32;
    const int nb = (wgid >> 1) * 16;
    half8 Bn[2];
    Bn[0] = *(const half8*)(x16 + (size_t)(nb + r16) * GC + quad * 8);
    Bn[1] = *(const half8*)(x16 + (size_t)(nb + r16) * GC + 32 + quad * 8);
    proj_mfma(Wf, Ws, Bn, cb, nb + r16, P2);
}

// ---------- K_bnproj: BN apply (layer l) fused with proj (layer l+1) ----------
// Block handles 32 nodes: BN elementwise -> x, x16, LDS; barrier; 4 waves do proj MFMA.
__global__ __launch_bounds__(256) void bnproj_kernel(
    const float* __restrict__ xn, const float* __restrict__ stats,
    const float* __restrict__ gamma, const float* __restrict__ beta,
    float* __restrict__ xout, _Float16* __restrict__ x16,
    const float* __restrict__ Wf, const float* __restrict__ Ws,  // next layer rows 0..63
    half2v* __restrict__ P2)
{
    __shared__ _Float16 lx[32 * 72];   // 72-half row pad -> 2-way (free) LDS banks
    const int nb = blockIdx.x * 32;
    const float invN = 1.0f / (float)N_NODES;

#pragma unroll
    for (int rep = 0; rep < 2; rep++) {
        int g = rep * 256 + threadIdx.x;        // granule within block: 0..511
        int gi = blockIdx.x * 512 + g;          // global float4 granule
        int node = g >> 4;                      // 0..31
        int c4 = (g & 15) * 4;
        float4 v = ((const float4*)xn)[gi];
        float vv[4] = {v.x, v.y, v.z, v.w};
        float o[4];
#pragma unroll
        for (int t = 0; t < 4; t++) {
            int c = c4 + t;
            float mu = stats[c] * invN;
            float var = stats[64 + c] * invN - mu * mu;
            float sc = gamma[c] * rsqrtf(var + BN_EPS);
            o[t] = (vv[t] - mu) * sc + beta[c];
        }
        ((float4*)xout)[gi] = make_float4(o[0], o[1], o[2], o[3]);
        half4 h = { (_Float16)o[0], (_Float16)o[1], (_Float16)o[2], (_Float16)o[3] };
        ((half4*)x16)[gi] = h;
        *(half4*)(lx + node * 72 + c4) = h;
    }
    __syncthreads();

    const int lane = threadIdx.x & 63;
    const int wid = threadIdx.x >> 6;
    const int quad = lane >> 4;
    const int r16 = lane & 15;
    const int cb = (wid & 1) * 32;
    const int tn = (wid >> 1) * 16 + r16;       // node within block's 32
    half8 Bn[2];
    Bn[0] = *(const half8*)(lx + tn * 72 + quad * 8);
    Bn[1] = *(const half8*)(lx + tn * 72 + 32 + quad * 8);
    proj_mfma(Wf, Ws, Bn, cb, nb + tn, P2);
}

// ---------- K5: flat-tile MFMA CGConv layer ----------
__global__ __launch_bounds__(256, 4) void tile_mfma_kernel(
    const _Float16* __restrict__ x16, const _Float16* __restrict__ ea,
    const int* __restrict__ csr_src, const int2* __restrict__ tdesc,
    const int* __restrict__ tcount, const float* __restrict__ inv_deg,
    const half2v* __restrict__ P2,
    const float* __restrict__ Wf, const float* __restrict__ Ws,   // [160][64]
    const float* __restrict__ bfv, const float* __restrict__ bsv, // [64]
    float* __restrict__ x)
{
    const int lane = threadIdx.x & 63;
    const int wid = threadIdx.x >> 6;
    const int quad = lane >> 4;
    const int r16 = lane & 15;

    const int wgid = blockIdx.x * 4 + wid;
    const int cthalf = wgid & 1;
    const int seq = wgid >> 1;
    const int NSEQ = TILE_GRID * 2;
    const int cb = cthalf * 32;

    // fp16 B fragments: kt=0,1 -> W rows 64..127 (src), kt=2 -> rows 128..159 (ea)
    half8 Bf[3][2], Bs[3][2];
#pragma unroll
    for (int kt = 0; kt < 3; kt++) {
#pragma unroll
        for (int ctl = 0; ctl < 2; ctl++) {
            int col = cb + ctl * 16 + r16;
            half8 bh, sh;
#pragma unroll
            for (int j = 0; j < 8; j++) {
                int k = 64 + kt * 32 + quad * 8 + j;
                bh[j] = (_Float16)Wf[k * GC + col];
                sh[j] = (_Float16)Ws[k * GC + col];
            }
            Bf[kt][ctl] = bh;
            Bs[kt][ctl] = sh;
        }
    }
    float biasf[2], biass[2];
#pragma unroll
    for (int ctl = 0; ctl < 2; ctl++) {
        int col = cb + ctl * 16 + r16;
        biasf[ctl] = bfv[col];
        biass[ctl] = bsv[col];
    }

    const int nt = tcount[0];
    if (seq >= nt) return;

    // ---- prologue ----
    int idx = seq;
    int2 d0 = tdesc[idx];
    int n0 = d0.y >> 5, c0 = d0.y & 31;
    int j0 = d0.x + (r16 < c0 ? r16 : c0 - 1);
    float inv0 = inv_deg[n0];
    int s0 = csr_src[j0];
    half8 cS0 = *(const half8*)(x16 + (size_t)s0 * GC + quad * 8);
    half8 cS1 = *(const half8*)(x16 + (size_t)s0 * GC + 32 + quad * 8);
    half8 cE  = *(const half8*)(ea + (size_t)j0 * RBF + quad * 8);
    U32H2 cP[2];
#pragma unroll
    for (int ctl = 0; ctl < 2; ctl++)
        cP[ctl].u = *(const unsigned int*)(P2 + (size_t)n0 * GC + cb + ctl * 16 + r16);

    int idx1 = idx + NSEQ;
    int2 d1 = tdesc[idx1 < nt ? idx1 : nt - 1];
    int n1 = d1.y >> 5, c1 = d1.y & 31;
    int j1 = d1.x + (r16 < c1 ? r16 : c1 - 1);
    int s1 = csr_src[j1];
    float inv1 = inv_deg[n1];

    int idx2 = idx1 + NSEQ;
    int2 d2 = tdesc[idx2 < nt ? idx2 : nt - 1];

    while (true) {
        // issue T+1 fragment + P loads
        half8 nS0 = *(const half8*)(x16 + (size_t)s1 * GC + quad * 8);
        half8 nS1 = *(const half8*)(x16 + (size_t)s1 * GC + 32 + quad * 8);
        half8 nE  = *(const half8*)(ea + (size_t)j1 * RBF + quad * 8);
        U32H2 nP[2];
#pragma unroll
        for (int ctl = 0; ctl < 2; ctl++)
            nP[ctl].u = *(const unsigned int*)(P2 + (size_t)n1 * GC + cb + ctl * 16 + r16);

        // T+2 meta
        int n2 = d2.y >> 5, c2 = d2.y & 31;
        int j2 = d2.x + (r16 < c2 ? r16 : c2 - 1);
        int s2 = csr_src[j2];
        float inv2 = inv_deg[n2];

        // T+3 desc
        int idx3 = idx2 + NSEQ;
        int2 d3 = tdesc[idx3 < nt ? idx3 : nt - 1];

        // ---- MFMA on tile T (acc init = dst-proj + bias, broadcast across edge rows) ----
        f32x4 cf[2], cs[2];
#pragma unroll
        for (int ctl = 0; ctl < 2; ctl++) {
            float fi = (float)cP[ctl].h.x + biasf[ctl];
            float si = (float)cP[ctl].h.y + biass[ctl];
            cf[ctl] = (f32x4){fi, fi, fi, fi};
            cs[ctl] = (f32x4){si, si, si, si};
        }
#pragma unroll
        for (int ctl = 0; ctl < 2; ctl++) {
            cf[ctl] = __builtin_amdgcn_mfma_f32_16x16x32_f16(cS0, Bf[0][ctl], cf[ctl], 0, 0, 0);
            cs[ctl] = __builtin_amdgcn_mfma_f32_16x16x32_f16(cS0, Bs[0][ctl], cs[ctl], 0, 0, 0);
            cf[ctl] = __builtin_amdgcn_mfma_f32_16x16x32_f16(cS1, Bf[1][ctl], cf[ctl], 0, 0, 0);
            cs[ctl] = __builtin_amdgcn_mfma_f32_16x16x32_f16(cS1, Bs[1][ctl], cs[ctl], 0, 0, 0);
            cf[ctl] = __builtin_amdgcn_mfma_f32_16x16x32_f16(cE,  Bf[2][ctl], cf[ctl], 0, 0, 0);
            cs[ctl] = __builtin_amdgcn_mfma_f32_16x16x32_f16(cE,  Bs[2][ctl], cs[ctl], 0, 0, 0);
        }

        // activation + reduce; C layout: col(lane&15)=chan, row(quad*4+rr)=edge
        float acc0 = 0.0f, acc1 = 0.0f;
#pragma unroll
        for (int ctl = 0; ctl < 2; ctl++) {
#pragma unroll
            for (int rr = 0; rr < 4; rr++) {
                float af = cf[ctl][rr];
                float as = cs[ctl][rr];
                float sg = 1.0f / (1.0f + __expf(-af));
                float sp = fmaxf(as, 0.0f) + __logf(1.0f + __expf(-fabsf(as)));
                float msg = (quad * 4 + rr < c0) ? sg * sp : 0.0f;
                if (ctl == 0) acc0 += msg; else acc1 += msg;
            }
        }
        acc0 += __shfl_xor(acc0, 16);
        acc0 += __shfl_xor(acc0, 32);
        acc1 += __shfl_xor(acc1, 16);
        acc1 += __shfl_xor(acc1, 32);
        if (lane < 32) {
            float a = (lane < 16) ? acc0 : acc1;
            atomicAdd(&x[(size_t)n0 * GC + cb + lane], a * inv0);
        }

        idx += NSEQ;
        if (idx >= nt) break;
        // rotate pipeline
        cS0 = nS0; cS1 = nS1; cE = nE;
        cP[0] = nP[0]; cP[1] = nP[1];
        n0 = n1; c0 = c1; inv0 = inv1;
        n1 = n2; c1 = c2; j1 = j2; s1 = s2; inv1 = inv2;
        d2 = d3; idx2 = idx3;
    }
}

// ---------- K6: BN stats ----------
__global__ __launch_bounds__(256) void stats_kernel(const float* __restrict__ x, float* __restrict__ stats)
{
    const int lane = threadIdx.x & 63;
    const int wid = threadIdx.x >> 6;
    int w = blockIdx.x * 4 + wid;
    float s1 = 0.0f, s2 = 0.0f;
    for (int n = w; n < N_NODES; n += 1024) {
        float v = x[(size_t)n * GC + lane];
        s1 += v;
        s2 = fmaf(v, v, s2);
    }
    __shared__ float rs1[4][64];
    __shared__ float rs2[4][64];
    rs1[wid][lane] = s1;
    rs2[wid][lane] = s2;
    __syncthreads();
    if (threadIdx.x < 64) {
        atomicAdd(&stats[lane], rs1[0][lane] + rs1[1][lane] + rs1[2][lane] + rs1[3][lane]);
    } else if (threadIdx.x < 128) {
        int c = threadIdx.x & 63;
        atomicAdd(&stats[64 + c], rs2[0][c] + rs2[1][c] + rs2[2][c] + rs2[3][c]);
    }
}

// ---------- K7: final batchnorm apply (layer 3 -> d_out) ----------
__global__ __launch_bounds__(256) void bn_kernel(
    const float* __restrict__ xn, const float* __restrict__ stats,
    const float* __restrict__ gamma, const float* __restrict__ beta,
    float* __restrict__ out)
{
    int i = blockIdx.x * 256 + threadIdx.x;
    int c4 = (i & 15) * 4;
    float4 v = ((const float4*)xn)[i];
    float vv[4] = {v.x, v.y, v.z, v.w};
    float o[4];
    const float invN = 1.0f / (float)N_NODES;
#pragma unroll
    for (int t = 0; t < 4; t++) {
        int c = c4 + t;
        float mu = stats[c] * invN;
        float var = stats[64 + c] * invN - mu * mu;
        float sc = gamma[c] * rsqrtf(var + BN_EPS);
        o[t] = (vv[t] - mu) * sc + beta[c];
    }
    ((float4*)out)[i] = make_float4(o[0], o[1], o[2], o[3]);
}

extern "C" void kernel_launch(void* const* d_in, const int* in_sizes, int n_in,
                              void* d_out, int out_size, void* d_ws, size_t ws_size,
                              hipStream_t stream)
{
    const int* atom_types = (const int*)d_in[0];
    const float* pos = (const float*)d_in[1];
    const int* edge_index = (const int*)d_in[2];
    const float* emb = (const float*)d_in[3];
    const float* pre_W = (const float*)d_in[4];
    const float* pre_b = (const float*)d_in[5];
    const float* Wf = (const float*)d_in[6];
    const float* bf = (const float*)d_in[7];
    const float* Ws = (const float*)d_in[8];
    const float* bs = (const float*)d_in[9];
    const float* gamma = (const float*)d_in[10];
    const float* beta = (const float*)d_in[11];
    const float* means = (const float*)d_in[12];
    const float* betas = (const float*)d_in[13];

    char* base = (char*)d_ws;
    char* p = base;
    auto alloc = [&](size_t bytes) -> char* {
        char* r = p;
        p += (bytes + 255) & ~(size_t)255;
        return r;
    };
    unsigned int* ea = (unsigned int*)alloc((size_t)N_EDGES * RBF * 2);   // 76.8 MB fp16
    float* x = (float*)alloc((size_t)N_NODES * GC * 4);                   // 25.6 MB
    _Float16* x16 = (_Float16*)alloc((size_t)N_NODES * GC * 2);           // 12.8 MB
    half2v* P2 = (half2v*)alloc((size_t)N_NODES * GC * 4);                // 25.6 MB {f,s}
    int* csr_src = (int*)alloc((size_t)N_EDGES * 4);                      // 4.8 MB
    int2* tdesc = (int2*)alloc((size_t)NTILE_MAX * 8);                    // 1.4 MB
    int* row_st = (int*)alloc((size_t)(N_NODES + 1) * 4);
    float* inv_deg = (float*)alloc((size_t)N_NODES * 4);
    float* T = (float*)alloc((size_t)NATOM * GC * 4);
    int* bsums = (int*)alloc(512 * 4);
    int* boffs = (int*)alloc(512 * 4);
    const size_t ZR_INTS = (size_t)2 * N_NODES + 128 * NLAYERS + 64;
    char* zr = alloc(ZR_INTS * 4);
    int* deg = (int*)zr;
    int* cursor = deg + N_NODES;
    float* stats = (float*)(cursor + N_NODES);
    int* tcount = (int*)(stats + 128 * NLAYERS);

    if ((size_t)(p - base) > ws_size) return;  // diagnostic bail

    hipMemsetAsync(zr, 0, ZR_INTS * 4, stream);

    const int EG = (N_EDGES + 255) / 256;
    deg_kernel<<<EG, 256, 0, stream>>>(edge_index, deg);
    scan_a_kernel<<<391, 256, 0, stream>>>(deg, bsums);
    scan_b_kernel<<<1, 512, 0, stream>>>(bsums, boffs);
    scan_c_kernel<<<391, 256, 0, stream>>>(deg, boffs, row_st, inv_deg);
    scatter_rbf_kernel<<<EG, 256, 0, stream>>>(edge_index, pos, row_st, cursor,
                                               means, betas, csr_src, ea);
    tile_build_kernel<<<391, 256, 0, stream>>>(row_st, tdesc, tcount);
    atom_table_kernel<<<NATOM, 64, 0, stream>>>(emb, pre_W, pre_b, T);
    xinit_kernel<<<N_NODES * 16 / 256, 256, 0, stream>>>(atom_types, T, x, x16);
    proj_kernel<<<N_NODES / 32, 256, 0, stream>>>(x16, Wf, Ws, P2);

    for (int l = 0; l < NLAYERS; l++) {
        const float* Wfl = Wf + (size_t)l * 160 * GC;
        const float* Wsl = Ws + (size_t)l * 160 * GC;
        tile_mfma_kernel<<<TILE_GRID, 256, 0, stream>>>(
            x16, (const _Float16*)ea, csr_src, tdesc, tcount, inv_deg, P2,
            Wfl, Wsl, bf + l * GC, bs + l * GC, x);
        stats_kernel<<<256, 256, 0, stream>>>(x, stats + l * 128);
        if (l < NLAYERS - 1) {
            bnproj_kernel<<<N_NODES / 32, 256, 0, stream>>>(
                x, stats + l * 128, gamma + l * GC, beta + l * GC,
                x, x16, Wfl + 160 * GC, Wsl + 160 * GC, P2);
        } else {
            bn_kernel<<<N_NODES * 16 / 256, 256, 0, stream>>>(
                x, stats + l * 128, gamma + l * GC, beta + l * GC, (float*)d_out);
        }
    }
}

// Round 9
// 930.275 us; speedup vs baseline: 1.9207x; 1.1151x over previous
//
#include <hip/hip_runtime.h>
#include <math.h>

#define N_NODES 100000
#define N_EDGES 1200000
#define GC 64
#define RBF 32
#define NLAYERS 4
#define NF 92
#define NATOM 100
#define BN_EPS 1e-5f
#define TILE_GRID 2048
#define NTILE_MAX 176000   // worst case N + E/16 = 175k

typedef _Float16 half8 __attribute__((ext_vector_type(8)));
typedef _Float16 half4 __attribute__((ext_vector_type(4)));
typedef _Float16 half2v __attribute__((ext_vector_type(2)));
typedef float f32x4 __attribute__((ext_vector_type(4)));
union U32H2 { unsigned int u; half2v h; };

// ---------- K1: degree histogram ----------
__global__ __launch_bounds__(256) void deg_kernel(
    const int* __restrict__ ei, int* __restrict__ deg)
{
    int e = blockIdx.x * 256 + threadIdx.x;
    if (e >= N_EDGES) return;
    atomicAdd(&deg[ei[N_EDGES + e]], 1);
}

// ---------- scan ----------
__global__ __launch_bounds__(256) void scan_a_kernel(const int* __restrict__ deg, int* __restrict__ bsums)
{
    __shared__ int sm[256];
    int tid = threadIdx.x;
    int i = blockIdx.x * 256 + tid;
    int v = (i < N_NODES) ? deg[i] : 0;
    sm[tid] = v;
    __syncthreads();
    for (int s = 128; s > 0; s >>= 1) {
        if (tid < s) sm[tid] += sm[tid + s];
        __syncthreads();
    }
    if (tid == 0) bsums[blockIdx.x] = sm[0];
}

__global__ __launch_bounds__(512) void scan_b_kernel(const int* __restrict__ bsums, int* __restrict__ boffs)
{
    __shared__ int sm[512];
    int tid = threadIdx.x;
    int v = (tid < 391) ? bsums[tid] : 0;
    sm[tid] = v;
    __syncthreads();
    for (int off = 1; off < 512; off <<= 1) {
        int t = (tid >= off) ? sm[tid - off] : 0;
        __syncthreads();
        sm[tid] += t;
        __syncthreads();
    }
    boffs[tid] = (tid == 0) ? 0 : sm[tid - 1];
}

__global__ __launch_bounds__(256) void scan_c_kernel(
    const int* __restrict__ deg, const int* __restrict__ boffs,
    int* __restrict__ row_st, float* __restrict__ inv_deg)
{
    __shared__ int sm[256];
    int tid = threadIdx.x;
    int i = blockIdx.x * 256 + tid;
    int v = (i < N_NODES) ? deg[i] : 0;
    sm[tid] = v;
    __syncthreads();
    for (int off = 1; off < 256; off <<= 1) {
        int t = (tid >= off) ? sm[tid - off] : 0;
        __syncthreads();
        sm[tid] += t;
        __syncthreads();
    }
    if (i <= N_NODES) row_st[i] = boffs[blockIdx.x] + sm[tid] - v;  // exclusive
    if (i < N_NODES) inv_deg[i] = (v > 0) ? (1.0f / (float)v) : 0.0f;
}

// ---------- K2: scatter edges into CSR order + fused RBF (fp16) ----------
__global__ __launch_bounds__(256) void scatter_rbf_kernel(
    const int* __restrict__ ei, const float* __restrict__ pos,
    const int* __restrict__ row_st, int* __restrict__ cursor,
    const float* __restrict__ means, const float* __restrict__ betas,
    int* __restrict__ csr_src, unsigned int* __restrict__ ea)
{
    int e = blockIdx.x * 256 + threadIdx.x;
    if (e >= N_EDGES) return;
    int s = ei[e];
    int d = ei[N_EDGES + e];
    float dx = pos[s * 3 + 0] - pos[d * 3 + 0];
    float dy = pos[s * 3 + 1] - pos[d * 3 + 1];
    float dz = pos[s * 3 + 2] - pos[d * 3 + 2];
    float dist = sqrtf(dx * dx + dy * dy + dz * dz + 1e-12f);

    int p = atomicAdd(&cursor[d], 1);
    int idx = row_st[d] + p;
    csr_src[idx] = s;

    float cut = 0.0f;
    if (dist < 5.0f) cut = 0.5f * (__cosf(dist * 0.6283185307179586f) + 1.0f);
    float ex = __expf(-dist);
    union { _Float16 h[32]; uint4 u[4]; } pk;
#pragma unroll
    for (int k = 0; k < 32; k++) {
        float v = ex - means[k];
        pk.h[k] = (_Float16)(cut * __expf(-betas[k] * v * v));
    }
    uint4* op = (uint4*)(ea + (size_t)idx * 16);
    op[0] = pk.u[0];
    op[1] = pk.u[1];
    op[2] = pk.u[2];
    op[3] = pk.u[3];
}

// ---------- K3: flat tile-descriptor list ----------
__global__ __launch_bounds__(256) void tile_build_kernel(
    const int* __restrict__ row_st, int2* __restrict__ tdesc, int* __restrict__ tcount)
{
    int n = blockIdx.x * 256 + threadIdx.x;
    if (n >= N_NODES) return;
    int row = row_st[n];
    int dg = row_st[n + 1] - row;
    int tiles = (dg + 15) >> 4;
    if (tiles == 0) return;
    int base = atomicAdd(tcount, tiles);
    for (int t = 0; t < tiles; t++) {
        int cnt = dg - 16 * t;
        if (cnt > 16) cnt = 16;
        tdesc[base + t] = make_int2(row + 16 * t, (n << 5) | cnt);
    }
}

// ---------- K4a: per-atom-type pre-layer table ----------
__global__ __launch_bounds__(64) void atom_table_kernel(
    const float* __restrict__ emb, const float* __restrict__ pre_W,
    const float* __restrict__ pre_b, float* __restrict__ T)
{
    int a = blockIdx.x;
    int c = threadIdx.x;
    float acc = pre_b[c];
    for (int k = 0; k < NF; k++) acc = fmaf(emb[a * NF + k], pre_W[k * GC + c], acc);
    T[a * GC + c] = fmaxf(acc, 0.0f);
}

// ---------- K4b: broadcast table to nodes ----------
__global__ __launch_bounds__(256) void xinit_kernel(
    const int* __restrict__ atom_types, const float* __restrict__ T,
    float* __restrict__ x, _Float16* __restrict__ x16)
{
    int i = blockIdx.x * 256 + threadIdx.x;  // i < N*16
    int n = i >> 4;
    int a = atom_types[n];
    float4 v = ((const float4*)T)[a * 16 + (i & 15)];
    ((float4*)x)[i] = v;
    half4 h = { (_Float16)v.x, (_Float16)v.y, (_Float16)v.z, (_Float16)v.w };
    ((half4*)x16)[i] = h;
}

// ---------- shared MFMA proj body: P2[n][c] = {f,s} interleaved half2 ----------
static __device__ __forceinline__ void proj_mfma(
    const float* __restrict__ Wf, const float* __restrict__ Ws,
    const half8 Bn[2], int cb, int node, half2v* __restrict__ P2)
{
    half8 Af[2][2], As[2][2];
    const int lane = threadIdx.x & 63;
    const int quad = lane >> 4;
    const int r16 = lane & 15;
#pragma unroll
    for (int kt = 0; kt < 2; kt++) {
#pragma unroll
        for (int sub = 0; sub < 2; sub++) {
            int chan = cb + sub * 16 + r16;
            half8 a, b;
#pragma unroll
            for (int j = 0; j < 8; j++) {
                int k = kt * 32 + quad * 8 + j;
                a[j] = (_Float16)Wf[k * GC + chan];
                b[j] = (_Float16)Ws[k * GC + chan];
            }
            Af[kt][sub] = a;
            As[kt][sub] = b;
        }
    }
    f32x4 accf[2], accs[2];
#pragma unroll
    for (int sub = 0; sub < 2; sub++) {
        accf[sub] = (f32x4){0.f, 0.f, 0.f, 0.f};
        accs[sub] = (f32x4){0.f, 0.f, 0.f, 0.f};
    }
#pragma unroll
    for (int kt = 0; kt < 2; kt++) {
#pragma unroll
        for (int sub = 0; sub < 2; sub++) {
            accf[sub] = __builtin_amdgcn_mfma_f32_16x16x32_f16(Af[kt][sub], Bn[kt], accf[sub], 0, 0, 0);
            accs[sub] = __builtin_amdgcn_mfma_f32_16x16x32_f16(As[kt][sub], Bn[kt], accs[sub], 0, 0, 0);
        }
    }
#pragma unroll
    for (int sub = 0; sub < 2; sub++) {
        half8 h = { (_Float16)accf[sub][0], (_Float16)accs[sub][0],
                    (_Float16)accf[sub][1], (_Float16)accs[sub][1],
                    (_Float16)accf[sub][2], (_Float16)accs[sub][2],
                    (_Float16)accf[sub][3], (_Float16)accs[sub][3] };
        *(half8*)(P2 + (size_t)node * GC + cb + sub * 16 + quad * 4) = h;
    }
}

// ---------- K_proj0: standalone proj (layer 0) ----------
__global__ __launch_bounds__(256) void proj_kernel(
    const _Float16* __restrict__ x16,
    const float* __restrict__ Wf, const float* __restrict__ Ws,
    half2v* __restrict__ P2)
{
    const int lane = threadIdx.x & 63;
    const int wid = threadIdx.x >> 6;
    const int quad = lane >> 4;
    const int r16 = lane & 15;
    const int wgid = blockIdx.x * 4 + wid;
    const int cb = (wgid & 1) * 32;
    const int nb = (wgid >> 1) * 16;
    half8 Bn[2];
    Bn[0] = *(const half8*)(x16 + (size_t)(nb + r16) * GC + quad * 8);
    Bn[1] = *(const half8*)(x16 + (size_t)(nb + r16) * GC + 32 + quad * 8);
    proj_mfma(Wf, Ws, Bn, cb, nb + r16, P2);
}

// ---------- K_bnproj: BN apply (layer l) fused with proj (layer l+1) ----------
__global__ __launch_bounds__(256) void bnproj_kernel(
    const float* __restrict__ xn, const float* __restrict__ stats,
    const float* __restrict__ gamma, const float* __restrict__ beta,
    float* __restrict__ xout, _Float16* __restrict__ x16,
    const float* __restrict__ Wf, const float* __restrict__ Ws,  // next layer rows 0..63
    half2v* __restrict__ P2)
{
    __shared__ _Float16 lx[32 * 72];   // 72-half row pad -> 2-way (free) LDS banks
    const int nb = blockIdx.x * 32;
    const float invN = 1.0f / (float)N_NODES;

#pragma unroll
    for (int rep = 0; rep < 2; rep++) {
        int g = rep * 256 + threadIdx.x;        // granule within block: 0..511
        int gi = blockIdx.x * 512 + g;          // global float4 granule
        int node = g >> 4;                      // 0..31
        int c4 = (g & 15) * 4;
        float4 v = ((const float4*)xn)[gi];
        float vv[4] = {v.x, v.y, v.z, v.w};
        float o[4];
#pragma unroll
        for (int t = 0; t < 4; t++) {
            int c = c4 + t;
            float mu = stats[c] * invN;
            float var = stats[64 + c] * invN - mu * mu;
            float sc = gamma[c] * rsqrtf(var + BN_EPS);
            o[t] = (vv[t] - mu) * sc + beta[c];
        }
        ((float4*)xout)[gi] = make_float4(o[0], o[1], o[2], o[3]);
        half4 h = { (_Float16)o[0], (_Float16)o[1], (_Float16)o[2], (_Float16)o[3] };
        ((half4*)x16)[gi] = h;
        *(half4*)(lx + node * 72 + c4) = h;
    }
    __syncthreads();

    const int lane = threadIdx.x & 63;
    const int wid = threadIdx.x >> 6;
    const int quad = lane >> 4;
    const int r16 = lane & 15;
    const int cb = (wid & 1) * 32;
    const int tn = (wid >> 1) * 16 + r16;       // node within block's 32
    half8 Bn[2];
    Bn[0] = *(const half8*)(lx + tn * 72 + quad * 8);
    Bn[1] = *(const half8*)(lx + tn * 72 + 32 + quad * 8);
    proj_mfma(Wf, Ws, Bn, cb, nb + tn, P2);
}

// ---------- compute body for one tile ----------
static __device__ __forceinline__ void compute_tile(
    int n0, int c0, float inv0,
    half8 S0, half8 S1, half8 E, U32H2 P0, U32H2 P1,
    const half8 (&Bf)[3][2], const half8 (&Bs)[3][2],
    const float (&biasf)[2], const float (&biass)[2],
    int lane, int quad, int cb, float* __restrict__ x)
{
    f32x4 cf[2], cs[2];
    {
        float fi0 = (float)P0.h.x + biasf[0];
        float si0 = (float)P0.h.y + biass[0];
        float fi1 = (float)P1.h.x + biasf[1];
        float si1 = (float)P1.h.y + biass[1];
        cf[0] = (f32x4){fi0, fi0, fi0, fi0};
        cs[0] = (f32x4){si0, si0, si0, si0};
        cf[1] = (f32x4){fi1, fi1, fi1, fi1};
        cs[1] = (f32x4){si1, si1, si1, si1};
    }
#pragma unroll
    for (int ctl = 0; ctl < 2; ctl++) {
        cf[ctl] = __builtin_amdgcn_mfma_f32_16x16x32_f16(S0, Bf[0][ctl], cf[ctl], 0, 0, 0);
        cs[ctl] = __builtin_amdgcn_mfma_f32_16x16x32_f16(S0, Bs[0][ctl], cs[ctl], 0, 0, 0);
        cf[ctl] = __builtin_amdgcn_mfma_f32_16x16x32_f16(S1, Bf[1][ctl], cf[ctl], 0, 0, 0);
        cs[ctl] = __builtin_amdgcn_mfma_f32_16x16x32_f16(S1, Bs[1][ctl], cs[ctl], 0, 0, 0);
        cf[ctl] = __builtin_amdgcn_mfma_f32_16x16x32_f16(E,  Bf[2][ctl], cf[ctl], 0, 0, 0);
        cs[ctl] = __builtin_amdgcn_mfma_f32_16x16x32_f16(E,  Bs[2][ctl], cs[ctl], 0, 0, 0);
    }
    float acc0 = 0.0f, acc1 = 0.0f;
#pragma unroll
    for (int ctl = 0; ctl < 2; ctl++) {
#pragma unroll
        for (int rr = 0; rr < 4; rr++) {
            float af = cf[ctl][rr];
            float as = cs[ctl][rr];
            float sg = __builtin_amdgcn_rcpf(1.0f + __expf(-af));   // fast rcp (was IEEE div)
            float sp = fmaxf(as, 0.0f) + __logf(1.0f + __expf(-fabsf(as)));
            float msg = (quad * 4 + rr < c0) ? sg * sp : 0.0f;
            if (ctl == 0) acc0 += msg; else acc1 += msg;
        }
    }
    acc0 += __shfl_xor(acc0, 16);
    acc0 += __shfl_xor(acc0, 32);
    acc1 += __shfl_xor(acc1, 16);
    acc1 += __shfl_xor(acc1, 32);
    if (lane < 32) {
        float a = (lane < 16) ? acc0 : acc1;
        atomicAdd(&x[(size_t)n0 * GC + cb + lane], a * inv0);
    }
}

// ---------- K5: flat-tile MFMA CGConv layer, 2-deep frag pipeline ----------
__global__ __launch_bounds__(256, 4) void tile_mfma_kernel(
    const _Float16* __restrict__ x16, const _Float16* __restrict__ ea,
    const int* __restrict__ csr_src, const int2* __restrict__ tdesc,
    const int* __restrict__ tcount, const float* __restrict__ inv_deg,
    const half2v* __restrict__ P2,
    const float* __restrict__ Wf, const float* __restrict__ Ws,   // [160][64]
    const float* __restrict__ bfv, const float* __restrict__ bsv, // [64]
    float* __restrict__ x)
{
    const int lane = threadIdx.x & 63;
    const int wid = threadIdx.x >> 6;
    const int quad = lane >> 4;
    const int r16 = lane & 15;

    const int wgid = blockIdx.x * 4 + wid;
    const int cthalf = wgid & 1;
    const int seq = wgid >> 1;
    const int NSEQ = TILE_GRID * 2;
    const int cb = cthalf * 32;

    half8 Bf[3][2], Bs[3][2];
#pragma unroll
    for (int kt = 0; kt < 3; kt++) {
#pragma unroll
        for (int ctl = 0; ctl < 2; ctl++) {
            int col = cb + ctl * 16 + r16;
            half8 bh, sh;
#pragma unroll
            for (int j = 0; j < 8; j++) {
                int k = 64 + kt * 32 + quad * 8 + j;
                bh[j] = (_Float16)Wf[k * GC + col];
                sh[j] = (_Float16)Ws[k * GC + col];
            }
            Bf[kt][ctl] = bh;
            Bs[kt][ctl] = sh;
        }
    }
    float biasf[2], biass[2];
#pragma unroll
    for (int ctl = 0; ctl < 2; ctl++) {
        int col = cb + ctl * 16 + r16;
        biasf[ctl] = bfv[col];
        biass[ctl] = bsv[col];
    }

    const int nt = tcount[0];
    if (seq >= nt) return;

    // ---- prologue: set A = tile T, set B = tile T+1, stage2 = T+2, desc3 = T+3 ----
    int idx = seq;
    int2 d = tdesc[idx];
    int nA = d.y >> 5, cA = d.y & 31;
    float invA = inv_deg[nA];
    int jA = d.x + (r16 < cA ? r16 : cA - 1);
    int sA = csr_src[jA];
    half8 AS0 = *(const half8*)(x16 + (size_t)sA * GC + quad * 8);
    half8 AS1 = *(const half8*)(x16 + (size_t)sA * GC + 32 + quad * 8);
    half8 AE  = *(const half8*)(ea + (size_t)jA * RBF + quad * 8);
    U32H2 AP0, AP1;
    AP0.u = *(const unsigned int*)(P2 + (size_t)nA * GC + cb + r16);
    AP1.u = *(const unsigned int*)(P2 + (size_t)nA * GC + cb + 16 + r16);

    int idx1 = idx + NSEQ;
    d = tdesc[idx1 < nt ? idx1 : nt - 1];
    int nB = d.y >> 5, cB = d.y & 31;
    float invB = inv_deg[nB];
    int jB = d.x + (r16 < cB ? r16 : cB - 1);
    int sB = csr_src[jB];
    half8 BS0 = *(const half8*)(x16 + (size_t)sB * GC + quad * 8);
    half8 BS1 = *(const half8*)(x16 + (size_t)sB * GC + 32 + quad * 8);
    half8 BE  = *(const half8*)(ea + (size_t)jB * RBF + quad * 8);
    U32H2 BP0, BP1;
    BP0.u = *(const unsigned int*)(P2 + (size_t)nB * GC + cb + r16);
    BP1.u = *(const unsigned int*)(P2 + (size_t)nB * GC + cb + 16 + r16);

    int idx2 = idx1 + NSEQ;
    d = tdesc[idx2 < nt ? idx2 : nt - 1];
    int n2 = d.y >> 5, c2 = d.y & 31;
    float inv2 = inv_deg[n2];
    int j2 = d.x + (r16 < c2 ? r16 : c2 - 1);
    int s2 = csr_src[j2];

    int idx3 = idx2 + NSEQ;
    int2 d3 = tdesc[idx3 < nt ? idx3 : nt - 1];

    while (true) {
        // ===== compute tile (set A) =====
        compute_tile(nA, cA, invA, AS0, AS1, AE, AP0, AP1,
                     Bf, Bs, biasf, biass, lane, quad, cb, x);
        // refill set A with stage2's tile (2 ahead of its compute)
        AS0 = *(const half8*)(x16 + (size_t)s2 * GC + quad * 8);
        AS1 = *(const half8*)(x16 + (size_t)s2 * GC + 32 + quad * 8);
        AE  = *(const half8*)(ea + (size_t)j2 * RBF + quad * 8);
        AP0.u = *(const unsigned int*)(P2 + (size_t)n2 * GC + cb + r16);
        AP1.u = *(const unsigned int*)(P2 + (size_t)n2 * GC + cb + 16 + r16);
        nA = n2; cA = c2; invA = inv2;
        // advance stage2 from desc3; issue csr; issue next desc
        n2 = d3.y >> 5; c2 = d3.y & 31;
        inv2 = inv_deg[n2];
        j2 = d3.x + (r16 < c2 ? r16 : c2 - 1);
        s2 = csr_src[j2];
        idx3 += NSEQ;
        d3 = tdesc[idx3 < nt ? idx3 : nt - 1];

        idx += NSEQ;
        if (idx >= nt) break;

        // ===== compute tile (set B) =====
        compute_tile(nB, cB, invB, BS0, BS1, BE, BP0, BP1,
                     Bf, Bs, biasf, biass, lane, quad, cb, x);
        BS0 = *(const half8*)(x16 + (size_t)s2 * GC + quad * 8);
        BS1 = *(const half8*)(x16 + (size_t)s2 * GC + 32 + quad * 8);
        BE  = *(const half8*)(ea + (size_t)j2 * RBF + quad * 8);
        BP0.u = *(const unsigned int*)(P2 + (size_t)n2 * GC + cb + r16);
        BP1.u = *(const unsigned int*)(P2 + (size_t)n2 * GC + cb + 16 + r16);
        nB = n2; cB = c2; invB = inv2;
        n2 = d3.y >> 5; c2 = d3.y & 31;
        inv2 = inv_deg[n2];
        j2 = d3.x + (r16 < c2 ? r16 : c2 - 1);
        s2 = csr_src[j2];
        idx3 += NSEQ;
        d3 = tdesc[idx3 < nt ? idx3 : nt - 1];

        idx += NSEQ;
        if (idx >= nt) break;
    }
}

// ---------- K6: BN stats ----------
__global__ __launch_bounds__(256) void stats_kernel(const float* __restrict__ x, float* __restrict__ stats)
{
    const int lane = threadIdx.x & 63;
    const int wid = threadIdx.x >> 6;
    int w = blockIdx.x * 4 + wid;
    float s1 = 0.0f, s2 = 0.0f;
    for (int n = w; n < N_NODES; n += 1024) {
        float v = x[(size_t)n * GC + lane];
        s1 += v;
        s2 = fmaf(v, v, s2);
    }
    __shared__ float rs1[4][64];
    __shared__ float rs2[4][64];
    rs1[wid][lane] = s1;
    rs2[wid][lane] = s2;
    __syncthreads();
    if (threadIdx.x < 64) {
        atomicAdd(&stats[lane], rs1[0][lane] + rs1[1][lane] + rs1[2][lane] + rs1[3][lane]);
    } else if (threadIdx.x < 128) {
        int c = threadIdx.x & 63;
        atomicAdd(&stats[64 + c], rs2[0][c] + rs2[1][c] + rs2[2][c] + rs2[3][c]);
    }
}

// ---------- K7: final batchnorm apply (layer 3 -> d_out) ----------
__global__ __launch_bounds__(256) void bn_kernel(
    const float* __restrict__ xn, const float* __restrict__ stats,
    const float* __restrict__ gamma, const float* __restrict__ beta,
    float* __restrict__ out)
{
    int i = blockIdx.x * 256 + threadIdx.x;
    int c4 = (i & 15) * 4;
    float4 v = ((const float4*)xn)[i];
    float vv[4] = {v.x, v.y, v.z, v.w};
    float o[4];
    const float invN = 1.0f / (float)N_NODES;
#pragma unroll
    for (int t = 0; t < 4; t++) {
        int c = c4 + t;
        float mu = stats[c] * invN;
        float var = stats[64 + c] * invN - mu * mu;
        float sc = gamma[c] * rsqrtf(var + BN_EPS);
        o[t] = (vv[t] - mu) * sc + beta[c];
    }
    ((float4*)out)[i] = make_float4(o[0], o[1], o[2], o[3]);
}

extern "C" void kernel_launch(void* const* d_in, const int* in_sizes, int n_in,
                              void* d_out, int out_size, void* d_ws, size_t ws_size,
                              hipStream_t stream)
{
    const int* atom_types = (const int*)d_in[0];
    const float* pos = (const float*)d_in[1];
    const int* edge_index = (const int*)d_in[2];
    const float* emb = (const float*)d_in[3];
    const float* pre_W = (const float*)d_in[4];
    const float* pre_b = (const float*)d_in[5];
    const float* Wf = (const float*)d_in[6];
    const float* bf = (const float*)d_in[7];
    const float* Ws = (const float*)d_in[8];
    const float* bs = (const float*)d_in[9];
    const float* gamma = (const float*)d_in[10];
    const float* beta = (const float*)d_in[11];
    const float* means = (const float*)d_in[12];
    const float* betas = (const float*)d_in[13];

    char* base = (char*)d_ws;
    char* p = base;
    auto alloc = [&](size_t bytes) -> char* {
        char* r = p;
        p += (bytes + 255) & ~(size_t)255;
        return r;
    };
    unsigned int* ea = (unsigned int*)alloc((size_t)N_EDGES * RBF * 2);   // 76.8 MB fp16
    float* x = (float*)alloc((size_t)N_NODES * GC * 4);                   // 25.6 MB
    _Float16* x16 = (_Float16*)alloc((size_t)N_NODES * GC * 2);           // 12.8 MB
    half2v* P2 = (half2v*)alloc((size_t)N_NODES * GC * 4);                // 25.6 MB {f,s}
    int* csr_src = (int*)alloc((size_t)N_EDGES * 4);                      // 4.8 MB
    int2* tdesc = (int2*)alloc((size_t)NTILE_MAX * 8);                    // 1.4 MB
    int* row_st = (int*)alloc((size_t)(N_NODES + 1) * 4);
    float* inv_deg = (float*)alloc((size_t)N_NODES * 4);
    float* T = (float*)alloc((size_t)NATOM * GC * 4);
    int* bsums = (int*)alloc(512 * 4);
    int* boffs = (int*)alloc(512 * 4);
    const size_t ZR_INTS = (size_t)2 * N_NODES + 128 * NLAYERS + 64;
    char* zr = alloc(ZR_INTS * 4);
    int* deg = (int*)zr;
    int* cursor = deg + N_NODES;
    float* stats = (float*)(cursor + N_NODES);
    int* tcount = (int*)(stats + 128 * NLAYERS);

    if ((size_t)(p - base) > ws_size) return;  // diagnostic bail

    hipMemsetAsync(zr, 0, ZR_INTS * 4, stream);

    const int EG = (N_EDGES + 255) / 256;
    deg_kernel<<<EG, 256, 0, stream>>>(edge_index, deg);
    scan_a_kernel<<<391, 256, 0, stream>>>(deg, bsums);
    scan_b_kernel<<<1, 512, 0, stream>>>(bsums, boffs);
    scan_c_kernel<<<391, 256, 0, stream>>>(deg, boffs, row_st, inv_deg);
    scatter_rbf_kernel<<<EG, 256, 0, stream>>>(edge_index, pos, row_st, cursor,
                                               means, betas, csr_src, ea);
    tile_build_kernel<<<391, 256, 0, stream>>>(row_st, tdesc, tcount);
    atom_table_kernel<<<NATOM, 64, 0, stream>>>(emb, pre_W, pre_b, T);
    xinit_kernel<<<N_NODES * 16 / 256, 256, 0, stream>>>(atom_types, T, x, x16);
    proj_kernel<<<N_NODES / 32, 256, 0, stream>>>(x16, Wf, Ws, P2);

    for (int l = 0; l < NLAYERS; l++) {
        const float* Wfl = Wf + (size_t)l * 160 * GC;
        const float* Wsl = Ws + (size_t)l * 160 * GC;
        tile_mfma_kernel<<<TILE_GRID, 256, 0, stream>>>(
            x16, (const _Float16*)ea, csr_src, tdesc, tcount, inv_deg, P2,
            Wfl, Wsl, bf + l * GC, bs + l * GC, x);
        stats_kernel<<<256, 256, 0, stream>>>(x, stats + l * 128);
        if (l < NLAYERS - 1) {
            bnproj_kernel<<<N_NODES / 32, 256, 0, stream>>>(
                x, stats + l * 128, gamma + l * GC, beta + l * GC,
                x, x16, Wfl + 160 * GC, Wsl + 160 * GC, P2);
        } else {
            bn_kernel<<<N_NODES * 16 / 256, 256, 0, stream>>>(
                x, stats + l * 128, gamma + l * GC, beta + l * GC, (float*)d_out);
        }
    }
}